// Round 2
// baseline (799.740 us; speedup 1.0000x reference)
//
#include <hip/hip_runtime.h>
#include <math.h>

namespace {

constexpr int kB = 64;
constexpr int kN = 4096;
constexpr int kM = 128;
constexpr int kH = 512;
constexpr int kE = 256;
constexpr int kO = 256;
constexpr int kGates = 4 * kH;       // 2048
constexpr int kCatW = 3 * kM + kH;   // 896  (read0|read1|read2|h)
constexpr int kPRow = 1600;          // padded 1572 (3*390 write + 3*134 read)
constexpr int kWN = kB * kN;

__device__ __forceinline__ float sigm_(float x) { return 1.f / (1.f + expf(-x)); }
__device__ __forceinline__ float softplus_(float x) { return x > 20.f ? x : log1pf(expf(x)); }

// =============== K1: gates GEMM (K-internal, no atomics) + misc init block ===============
__global__ __launch_bounds__(256) void gates_gemm(const float* __restrict__ x,
                                                  const float* __restrict__ W_ih,
                                                  const float* __restrict__ h_prev,
                                                  const float* __restrict__ W_hh,
                                                  float* __restrict__ gates,
                                                  const float* __restrict__ out_b,
                                                  float* __restrict__ out,
                                                  float* __restrict__ cat,
                                                  int* __restrict__ cnt) {
  if (blockIdx.x == 32) {   // init block
    const int tid = threadIdx.x;
    for (int i = tid; i < kB * kO; i += 256) out[i] = out_b[i & (kO - 1)];
    for (int i = tid; i < kB * 384; i += 256) cat[(i / 384) * kCatW + (i % 384)] = 0.f;
    for (int i = tid; i < 512; i += 256) cnt[i] = 0;
    return;
  }
  __shared__ float As[64][68];
  __shared__ float Ws[64][68];
  const int tid = threadIdx.x;
  const int j0 = blockIdx.x * 64;
  const int b0 = (tid & 15) * 4;
  const int j4 = (tid >> 4) * 4;
  float acc[4][4] = {};
  for (int kc = 0; kc < 12; kc++) {
    const bool isx = kc < 4;
    const float* A = isx ? x : h_prev;
    const float* W = isx ? W_ih : W_hh;
    const int lda = isx ? kE : kH;
    const int k0 = (isx ? kc : (kc - 4)) * 64;
    __syncthreads();
#pragma unroll
    for (int i = 0; i < 4; i++) {
      int idx = tid + i * 256;
      int bb = idx >> 4;
      int kk = (idx & 15) * 4;
      float4 v = *(const float4*)(A + (size_t)bb * lda + k0 + kk);
      As[kk][bb] = v.x; As[kk + 1][bb] = v.y; As[kk + 2][bb] = v.z; As[kk + 3][bb] = v.w;
      float4 w = *(const float4*)(W + (size_t)(j0 + bb) * lda + k0 + kk);
      Ws[kk][bb] = w.x; Ws[kk + 1][bb] = w.y; Ws[kk + 2][bb] = w.z; Ws[kk + 3][bb] = w.w;
    }
    __syncthreads();
#pragma unroll 2
    for (int k = 0; k < 64; k++) {
      float4 av = *(const float4*)&As[k][b0];
      float4 wv = *(const float4*)&Ws[k][j4];
      float aa[4] = {av.x, av.y, av.z, av.w};
      float ww[4] = {wv.x, wv.y, wv.z, wv.w};
#pragma unroll
      for (int ii = 0; ii < 4; ii++)
#pragma unroll
        for (int jj = 0; jj < 4; jj++) acc[ii][jj] += aa[ii] * ww[jj];
    }
  }
#pragma unroll
  for (int ii = 0; ii < 4; ii++) {
    float4 st = make_float4(acc[ii][0], acc[ii][1], acc[ii][2], acc[ii][3]);
    *(float4*)&gates[(size_t)(b0 + ii) * kGates + j0 + j4] = st;
  }
}

// =============== LSTM nonlinearity: gates(+biases) -> h into cat[:,384:] ===============
__global__ __launch_bounds__(256) void lstm_nl(const float* __restrict__ gates,
                                               const float* __restrict__ b_ih,
                                               const float* __restrict__ b_hh,
                                               const float* __restrict__ c_prev,
                                               float* __restrict__ cat) {
  int idx = blockIdx.x * 256 + threadIdx.x;
  if (idx >= kB * kH) return;
  int b = idx >> 9;
  int hh = idx & (kH - 1);
  const float* g = gates + (size_t)b * kGates;
  float i_ = g[hh]          + b_ih[hh]          + b_hh[hh];
  float f_ = g[kH + hh]     + b_ih[kH + hh]     + b_hh[kH + hh];
  float g_ = g[2 * kH + hh] + b_ih[2 * kH + hh] + b_hh[2 * kH + hh];
  float o_ = g[3 * kH + hh] + b_ih[3 * kH + hh] + b_hh[3 * kH + hh];
  float c = sigm_(f_) * c_prev[idx] + sigm_(i_) * tanhf(g_);
  float h = sigm_(o_) * tanhf(c);
  cat[(size_t)b * kCatW + 3 * kM + hh] = h;
}

// =============== K2: head projections GEMM (K-internal, direct store) ===============
__global__ __launch_bounds__(256) void proj_gemm(const float* __restrict__ cat,
                                                 const float* __restrict__ write_W,
                                                 const float* __restrict__ read_W,
                                                 float* __restrict__ praw) {
  __shared__ float As[64][68];
  __shared__ float Ws[64][68];
  const float* A = cat + 3 * kM;  // h, lda = kCatW
  const int tid = threadIdx.x;
  const int j0 = blockIdx.x * 64;
  const int b0 = (tid & 15) * 4;
  const int j4 = (tid >> 4) * 4;
  float acc[4][4] = {};
  for (int kc = 0; kc < 8; kc++) {
    const int k0 = kc * 64;
    __syncthreads();
#pragma unroll
    for (int i = 0; i < 4; i++) {
      int idx = tid + i * 256;
      int bb = idx >> 4;
      int kk = (idx & 15) * 4;
      float4 v = *(const float4*)(A + (size_t)bb * kCatW + k0 + kk);
      As[kk][bb] = v.x; As[kk + 1][bb] = v.y; As[kk + 2][bb] = v.z; As[kk + 3][bb] = v.w;
      int j = j0 + bb;
      float4 w = make_float4(0.f, 0.f, 0.f, 0.f);
      if (j < 1170)       w = *(const float4*)(write_W + (size_t)j * kH + k0 + kk);
      else if (j < 1572)  w = *(const float4*)(read_W + (size_t)(j - 1170) * kH + k0 + kk);
      Ws[kk][bb] = w.x; Ws[kk + 1][bb] = w.y; Ws[kk + 2][bb] = w.z; Ws[kk + 3][bb] = w.w;
    }
    __syncthreads();
#pragma unroll 2
    for (int k = 0; k < 64; k++) {
      float4 av = *(const float4*)&As[k][b0];
      float4 wv = *(const float4*)&Ws[k][j4];
      float aa[4] = {av.x, av.y, av.z, av.w};
      float ww[4] = {wv.x, wv.y, wv.z, wv.w};
#pragma unroll
      for (int ii = 0; ii < 4; ii++)
#pragma unroll
        for (int jj = 0; jj < 4; jj++) acc[ii][jj] += aa[ii] * ww[jj];
    }
  }
  if (j0 + j4 < 1572) {   // 1572 % 4 == 0 so quads never straddle
#pragma unroll
    for (int ii = 0; ii < 4; ii++) {
      float4 st = make_float4(acc[ii][0], acc[ii][1], acc[ii][2], acc[ii][3]);
      *(float4*)&praw[(size_t)(b0 + ii) * kPRow + j0 + j4] = st;
    }
  }
}

// =============== split head params; biases + nonlinearities ===============
__global__ __launch_bounds__(128) void split_params(const float* __restrict__ praw,
                                                    const float* __restrict__ write_b,
                                                    const float* __restrict__ read_b,
                                                    float* __restrict__ kwb, float* __restrict__ krb,
                                                    float* __restrict__ evb, float* __restrict__ avb,
                                                    float* __restrict__ scal) {
  const int b = blockIdx.x;
  const int m = threadIdx.x;
  __shared__ float red[2];
  for (int i = 0; i < 3; i++) {  // write heads
    const float* p = praw + (size_t)b * kPRow + i * 390;
    const float* wb = write_b + i * 390;
    float kv = p[m] + wb[m];
    kwb[((size_t)i * kB + b) * kM + m] = kv;
    evb[((size_t)i * kB + b) * kM + m] = sigm_(p[134 + m] + wb[134 + m]);
    avb[((size_t)i * kB + b) * kM + m] = p[262 + m] + wb[262 + m];
    float sq = kv * kv;
#pragma unroll
    for (int mm = 1; mm < 64; mm <<= 1) sq += __shfl_xor(sq, mm, 64);
    __syncthreads();
    if ((m & 63) == 0) red[m >> 6] = sq;
    __syncthreads();
    if (m == 0) {
      float* s = scal + ((size_t)i * kB + b) * 8;
      s[0] = softplus_(p[128] + wb[128]);
      s[1] = sigm_(p[129] + wb[129]);
      s[2] = 1.f + softplus_(p[133] + wb[133]);
      float x0 = p[130] + wb[130], x1 = p[131] + wb[131], x2 = p[132] + wb[132];
      float mx = fmaxf(x0, fmaxf(x1, x2));
      float e0 = expf(x0 - mx), e1 = expf(x1 - mx), e2 = expf(x2 - mx);
      float si = 1.f / (e0 + e1 + e2);
      s[3] = e0 * si; s[4] = e1 * si; s[5] = e2 * si;
      s[6] = sqrtf(red[0] + red[1]);
    }
  }
  for (int i = 0; i < 3; i++) {  // read heads
    const float* p = praw + (size_t)b * kPRow + 1170 + i * 134;
    const float* rb = read_b + i * 134;
    float kv = p[m] + rb[m];
    krb[((size_t)i * kB + b) * kM + m] = kv;
    float sq = kv * kv;
#pragma unroll
    for (int mm = 1; mm < 64; mm <<= 1) sq += __shfl_xor(sq, mm, 64);
    __syncthreads();
    if ((m & 63) == 0) red[m >> 6] = sq;
    __syncthreads();
    if (m == 0) {
      float* s = scal + ((size_t)(3 + i) * kB + b) * 8;
      s[0] = softplus_(p[128] + rb[128]);
      s[1] = sigm_(p[129] + rb[129]);
      s[2] = 1.f + softplus_(p[133] + rb[133]);
      float x0 = p[130] + rb[130], x1 = p[131] + rb[131], x2 = p[132] + rb[132];
      float mx = fmaxf(x0, fmaxf(x1, x2));
      float e0 = expf(x0 - mx), e1 = expf(x1 - mx), e2 = expf(x2 - mx);
      float si = 1.f / (e0 + e1 + e2);
      s[3] = e0 * si; s[4] = e1 * si; s[5] = e2 * si;
      s[6] = sqrtf(red[0] + red[1]);
    }
  }
}

// =============== addressing tail (runs inside bank_pass, one block per (b,head)) ===============
__device__ void addr_tail(const float* __restrict__ S, const float* __restrict__ R,
                          const float* __restrict__ sc, const float* __restrict__ wp,
                          float* __restrict__ wo, float* wb, float* red, int tid) {
  const float beta = sc[0], g = sc[1], r = sc[2];
  const float s0 = sc[3], s1 = sc[4], s2 = sc[5], kn = sc[6];
  const int lane = tid & 63, wid = tid >> 6;
  float loc[16];
  float mx = -1e30f;
#pragma unroll
  for (int i = 0; i < 16; i++) {
    int n = tid + i * 256;
    float denom = fmaxf(sqrtf(R[n]) * kn, 1e-8f);
    float v = beta * S[n] / denom;
    loc[i] = v;
    mx = fmaxf(mx, v);
  }
#pragma unroll
  for (int m = 1; m < 64; m <<= 1) mx = fmaxf(mx, __shfl_xor(mx, m, 64));
  __syncthreads();
  if (lane == 0) red[wid] = mx;
  __syncthreads();
  mx = fmaxf(fmaxf(red[0], red[1]), fmaxf(red[2], red[3]));
  float sum = 0.f;
#pragma unroll
  for (int i = 0; i < 16; i++) { loc[i] = expf(loc[i] - mx); sum += loc[i]; }
#pragma unroll
  for (int m = 1; m < 64; m <<= 1) sum += __shfl_xor(sum, m, 64);
  __syncthreads();
  if (lane == 0) red[wid] = sum;
  __syncthreads();
  sum = red[0] + red[1] + red[2] + red[3];
  const float inv = 1.f / sum;
  const float omg = 1.f - g;
#pragma unroll
  for (int i = 0; i < 16; i++) {
    int n = tid + i * 256;
    wb[n] = loc[i] * inv + omg * wp[n];
  }
  __syncthreads();
  float ssum = 0.f;
#pragma unroll
  for (int i = 0; i < 16; i++) {
    int n = tid + i * 256;
    float sh = s0 * wb[(n + kN - 1) & (kN - 1)] + s1 * wb[n] + s2 * wb[(n + 1) & (kN - 1)];
    float y = powf(sh, r);
    loc[i] = y;
    ssum += y;
  }
#pragma unroll
  for (int m = 1; m < 64; m <<= 1) ssum += __shfl_xor(ssum, m, 64);
  __syncthreads();
  if (lane == 0) red[wid] = ssum;
  __syncthreads();
  ssum = red[0] + red[1] + red[2] + red[3];
  const float invs = 1.f / (ssum + 1e-8f);
#pragma unroll
  for (int i = 0; i < 16; i++) {
    int n = tid + i * 256;
    wo[n] = loc[i] * invs;
  }
  __syncthreads();
}

// =============== bank pass: chain recompute + dots/norms + reads + fused addressing ===============
struct BankArgs {
  const float* bank;
  const float* cw[3];   // chain write weights (B,N)
  const float* ev[3];   // erase vectors (B,M)
  const float* av[3];   // add vectors (B,M)
  const float* rw[3];   // read weights applied after chain step j (B,N), or null
  float* ro[3];         // readout column base (row stride kCatW)
  const float* k1;      // score key for head 0 (B,M)
  const float* k2;      // score key for head 1 (B,M)
  float* s1; float* s2; float* ssq;  // (B,N) raw-score outputs (per-pass buffers)
  // fused addressing (per head)
  const float* scal0; const float* wp0; float* wo0;
  const float* scal1; const float* wp1; float* wo1;
  int* cnt;             // per-pass base: kB*2 ints, pre-zeroed
};

template <int NC, int NH>
__global__ __launch_bounds__(256) void bank_pass(BankArgs A) {
  const int b = blockIdx.y;
  const int tid = threadIdx.x;
  const int lane = tid & 63;
  const int wv = tid >> 6;
  const int sub = lane >> 4;
  const int lm = lane & 15;
  const int m8 = lm * 8;
  constexpr int NCA = (NC > 0) ? NC : 1;
  float e_r[NCA][8], a_r[NCA][8];
#pragma unroll
  for (int j = 0; j < NC; j++)
#pragma unroll
    for (int t = 0; t < 8; t++) {
      e_r[j][t] = A.ev[j][b * kM + m8 + t];
      a_r[j][t] = A.av[j][b * kM + m8 + t];
    }
  float k1r[8] = {}, k2r[8] = {};
  if (NH >= 1) {
#pragma unroll
    for (int t = 0; t < 8; t++) k1r[t] = A.k1[b * kM + m8 + t];
  }
  if (NH >= 2) {
#pragma unroll
    for (int t = 0; t < 8; t++) k2r[t] = A.k2[b * kM + m8 + t];
  }
  float racc[3][8];
#pragma unroll
  for (int j = 0; j < 3; j++)
#pragma unroll
    for (int t = 0; t < 8; t++) racc[j][t] = 0.f;
  __shared__ float rlds[3][kM];
  __shared__ float wb_s[kN];
  __shared__ float red_s[4];
  __shared__ int job_s;
  if (tid < kM) { rlds[0][tid] = 0.f; rlds[1][tid] = 0.f; rlds[2][tid] = 0.f; }

  const size_t bbase = (size_t)b * kN * kM;
  const size_t brow = (size_t)b * kN;
#pragma unroll 2
  for (int it = 0; it < 16; it++) {
    const int row = blockIdx.x * 256 + it * 16 + wv * 4 + sub;
    const float* rp = A.bank + bbase + (size_t)row * kM + m8;
    float4 u0 = *(const float4*)rp;
    float4 u1 = *(const float4*)(rp + 4);
    float v[8] = {u0.x, u0.y, u0.z, u0.w, u1.x, u1.y, u1.z, u1.w};
#pragma unroll
    for (int j = 0; j < NC; j++) {
      const float wj = A.cw[j][brow + row];
#pragma unroll
      for (int t = 0; t < 8; t++) v[t] += wj * (a_r[j][t] - e_r[j][t] * v[t]);
      if (A.rw[j]) {
        const float rv = A.rw[j][brow + row];
#pragma unroll
        for (int t = 0; t < 8; t++) racc[j][t] += rv * v[t];
      }
    }
    if (NH >= 1) {
      float d1 = 0.f, d2 = 0.f, sq = 0.f;
#pragma unroll
      for (int t = 0; t < 8; t++) { d1 += v[t] * k1r[t]; sq += v[t] * v[t]; }
      if (NH >= 2) {
#pragma unroll
        for (int t = 0; t < 8; t++) d2 += v[t] * k2r[t];
      }
#pragma unroll
      for (int m = 1; m < 16; m <<= 1) {
        d1 += __shfl_xor(d1, m, 64);
        sq += __shfl_xor(sq, m, 64);
        if (NH >= 2) d2 += __shfl_xor(d2, m, 64);
      }
      if (lm == 0) {
        A.s1[brow + row] = d1;
        A.ssq[brow + row] = sq;
        if (NH >= 2) A.s2[brow + row] = d2;
      }
    }
  }
  // read accumulation epilogue
  if (A.rw[0] || A.rw[1] || A.rw[2]) {
    __syncthreads();
#pragma unroll
    for (int j = 0; j < 3; j++) {
      if (!A.rw[j]) continue;
#pragma unroll
      for (int t = 0; t < 8; t++) {
        racc[j][t] += __shfl_xor(racc[j][t], 16, 64);
        racc[j][t] += __shfl_xor(racc[j][t], 32, 64);
      }
      if (sub == 0) {
#pragma unroll
        for (int t = 0; t < 8; t++) atomicAdd(&rlds[j][m8 + t], racc[j][t]);
      }
    }
    __syncthreads();
    if (tid < kM) {
#pragma unroll
      for (int j = 0; j < 3; j++)
        if (A.rw[j]) atomicAdd(&A.ro[j][(size_t)b * kCatW + tid], rlds[j][tid]);
    }
  }
  // fused addressing tail: last finisher of each (b,head) runs the softmax chain
  if (NH > 0) {
    __syncthreads();                  // drains all this block's score stores (vmcnt 0)
    if (tid == 0) {
      __threadfence();                // device-scope release: flush to L3
      int j = 0;
      if (atomicAdd(&A.cnt[b * 2 + 0], 1) == 15) j |= 1;
      if (NH > 1 && atomicAdd(&A.cnt[b * 2 + 1], 1) == 15) j |= 2;
      job_s = j;
    }
    __syncthreads();
    const int job = job_s;
    if (job) {
      __threadfence();                // acquire: invalidate before reading remote scores
      if (job & 1)
        addr_tail(A.s1 + brow, A.ssq + brow, A.scal0 + b * 8, A.wp0 + brow, A.wo0 + brow,
                  wb_s, red_s, tid);
      if (job & 2)
        addr_tail(A.s2 + brow, A.ssq + brow, A.scal1 + b * 8, A.wp1 + brow, A.wo1 + brow,
                  wb_s, red_s, tid);
    }
  }
}

// =============== out GEMM: split-K atomic (out pre-initialized with bias) ===============
__global__ __launch_bounds__(256) void out_gemm(const float* __restrict__ A,
                                                const float* __restrict__ W,
                                                float* __restrict__ C) {
  __shared__ float As[64][68];
  __shared__ float Ws[64][68];
  const int tid = threadIdx.x;
  const int j0 = blockIdx.x * 64;
  const int b0 = (tid & 15) * 4;
  const int j4 = (tid >> 4) * 4;
  float acc[4][4] = {};
  for (int kc = 0; kc < 2; kc++) {
    const int k0 = blockIdx.y * 128 + kc * 64;
    __syncthreads();
#pragma unroll
    for (int i = 0; i < 4; i++) {
      int idx = tid + i * 256;
      int bb = idx >> 4;
      int kk = (idx & 15) * 4;
      float4 v = *(const float4*)(A + (size_t)bb * kCatW + k0 + kk);
      As[kk][bb] = v.x; As[kk + 1][bb] = v.y; As[kk + 2][bb] = v.z; As[kk + 3][bb] = v.w;
      float4 w = *(const float4*)(W + (size_t)(j0 + bb) * kCatW + k0 + kk);
      Ws[kk][bb] = w.x; Ws[kk + 1][bb] = w.y; Ws[kk + 2][bb] = w.z; Ws[kk + 3][bb] = w.w;
    }
    __syncthreads();
#pragma unroll 2
    for (int k = 0; k < 64; k++) {
      float4 av = *(const float4*)&As[k][b0];
      float4 wv = *(const float4*)&Ws[k][j4];
      float aa[4] = {av.x, av.y, av.z, av.w};
      float ww[4] = {wv.x, wv.y, wv.z, wv.w};
#pragma unroll
      for (int ii = 0; ii < 4; ii++)
#pragma unroll
        for (int jj = 0; jj < 4; jj++) acc[ii][jj] += aa[ii] * ww[jj];
    }
  }
#pragma unroll
  for (int ii = 0; ii < 4; ii++)
#pragma unroll
    for (int jj = 0; jj < 4; jj++)
      atomicAdd(&C[(size_t)(b0 + ii) * kO + j0 + j4 + jj], acc[ii][jj]);
}

}  // namespace

extern "C" void kernel_launch(void* const* d_in, const int* in_sizes, int n_in,
                              void* d_out, int out_size, void* d_ws, size_t ws_size,
                              hipStream_t stream) {
  const float* x            = (const float*)d_in[0];
  const float* h_prev       = (const float*)d_in[1];
  const float* c_prev       = (const float*)d_in[2];
  const float* bank         = (const float*)d_in[3];
  const float* read_w_prev  = (const float*)d_in[4];
  const float* write_w_prev = (const float*)d_in[5];
  const float* W_ih         = (const float*)d_in[6];
  const float* W_hh         = (const float*)d_in[7];
  const float* b_ih         = (const float*)d_in[8];
  const float* b_hh         = (const float*)d_in[9];
  const float* read_W       = (const float*)d_in[10];
  const float* read_b       = (const float*)d_in[11];
  const float* write_W      = (const float*)d_in[12];
  const float* write_b      = (const float*)d_in[13];
  const float* out_W        = (const float*)d_in[14];
  const float* out_b        = (const float*)d_in[15];
  float* out = (float*)d_out;

  float* ws    = (float*)d_ws;
  float* gates = ws;                         // 64*2048
  float* praw  = gates + kB * kGates;        // 64*1600
  float* cat   = praw + kB * kPRow;          // 64*896
  float* kwb   = cat + kB * kCatW;           // 3*64*128
  float* krb   = kwb + 3 * kB * kM;
  float* evb   = krb + 3 * kB * kM;
  float* avb   = evb + 3 * kB * kM;
  float* scal  = avb + 3 * kB * kM;          // 6*64*8
  float* wwv   = scal + 6 * kB * 8;          // 3*64*4096
  float* wrv   = wwv + 3 * kWN;              // 3*64*4096
  float* sc_p  = wrv + 3 * kWN;              // 10 per-pass score buffers
  float* S_p1  = sc_p + 0 * kWN;  float* Q_p1 = sc_p + 1 * kWN;
  float* Sa_p2 = sc_p + 2 * kWN;  float* Sb_p2 = sc_p + 3 * kWN;  float* Q_p2 = sc_p + 4 * kWN;
  float* Sa_p3 = sc_p + 5 * kWN;  float* Sb_p3 = sc_p + 6 * kWN;  float* Q_p3 = sc_p + 7 * kWN;
  float* S_p4  = sc_p + 8 * kWN;  float* Q_p4 = sc_p + 9 * kWN;
  int* cnt = (int*)(sc_p + 10 * kWN);        // 512 ints (4 passes * 64 * 2)

  // ---- preamble ----
  gates_gemm<<<33, 256, 0, stream>>>(x, W_ih, h_prev, W_hh, gates, out_b, out, cat, cnt);
  lstm_nl<<<(kB * kH) / 256, 256, 0, stream>>>(gates, b_ih, b_hh, c_prev, cat);
  proj_gemm<<<25, 256, 0, stream>>>(cat, write_W, read_W, praw);
  split_params<<<64, 128, 0, stream>>>(praw, write_b, read_b, kwb, krb, evb, avb, scal);

  // ---- P1: scores(B0; kw0) + A1(ww0) ----
  {
    BankArgs p = {};
    p.bank = bank;
    p.k1 = kwb; p.s1 = S_p1; p.ssq = Q_p1;
    p.scal0 = scal + 0; p.wp0 = write_w_prev; p.wo0 = wwv;
    p.cnt = cnt + 0 * 128;
    bank_pass<0, 1><<<dim3(16, kB), 256, 0, stream>>>(p);
  }
  // ---- P2: scores(B1; kr0, kw1) + A2(wr0, ww1) ----
  {
    BankArgs p = {};
    p.bank = bank;
    p.cw[0] = wwv; p.ev[0] = evb; p.av[0] = avb;
    p.k1 = krb;             p.s1 = Sa_p2;
    p.k2 = kwb + kB * kM;   p.s2 = Sb_p2;
    p.ssq = Q_p2;
    p.scal0 = scal + (size_t)3 * kB * 8; p.wp0 = read_w_prev;        p.wo0 = wrv;
    p.scal1 = scal + (size_t)1 * kB * 8; p.wp1 = write_w_prev + kWN; p.wo1 = wwv + kWN;
    p.cnt = cnt + 1 * 128;
    bank_pass<1, 2><<<dim3(16, kB), 256, 0, stream>>>(p);
  }
  // ---- P3: read0 from B1; scores(B2; kr1, kw2) + A3(wr1, ww2) ----
  {
    BankArgs p = {};
    p.bank = bank;
    p.cw[0] = wwv;        p.ev[0] = evb;            p.av[0] = avb;
    p.cw[1] = wwv + kWN;  p.ev[1] = evb + kB * kM;  p.av[1] = avb + kB * kM;
    p.rw[0] = wrv; p.ro[0] = cat;                  // read0 -> cat[:,0:128]
    p.k1 = krb + kB * kM;     p.s1 = Sa_p3;
    p.k2 = kwb + 2 * kB * kM; p.s2 = Sb_p3;
    p.ssq = Q_p3;
    p.scal0 = scal + (size_t)4 * kB * 8; p.wp0 = read_w_prev + kWN;      p.wo0 = wrv + kWN;
    p.scal1 = scal + (size_t)2 * kB * 8; p.wp1 = write_w_prev + 2 * kWN; p.wo1 = wwv + 2 * kWN;
    p.cnt = cnt + 2 * 128;
    bank_pass<2, 2><<<dim3(16, kB), 256, 0, stream>>>(p);
  }
  // ---- P4: scores(B3; kr2) + A4(wr2) ----
  {
    BankArgs p = {};
    p.bank = bank;
    p.cw[0] = wwv;           p.ev[0] = evb;                p.av[0] = avb;
    p.cw[1] = wwv + kWN;     p.ev[1] = evb + kB * kM;      p.av[1] = avb + kB * kM;
    p.cw[2] = wwv + 2 * kWN; p.ev[2] = evb + 2 * kB * kM;  p.av[2] = avb + 2 * kB * kM;
    p.k1 = krb + 2 * kB * kM; p.s1 = S_p4; p.ssq = Q_p4;
    p.scal0 = scal + (size_t)5 * kB * 8; p.wp0 = read_w_prev + 2 * kWN; p.wo0 = wrv + 2 * kWN;
    p.cnt = cnt + 3 * 128;
    bank_pass<3, 1><<<dim3(16, kB), 256, 0, stream>>>(p);
  }
  // ---- P5: read1 from B2, read2 from B3 ----
  {
    BankArgs p = {};
    p.bank = bank;
    p.cw[0] = wwv;           p.ev[0] = evb;                p.av[0] = avb;
    p.cw[1] = wwv + kWN;     p.ev[1] = evb + kB * kM;      p.av[1] = avb + kB * kM;
    p.cw[2] = wwv + 2 * kWN; p.ev[2] = evb + 2 * kB * kM;  p.av[2] = avb + 2 * kB * kM;
    p.rw[1] = wrv + kWN;     p.ro[1] = cat + kM;       // read1 -> cat[:,128:256]
    p.rw[2] = wrv + 2 * kWN; p.ro[2] = cat + 2 * kM;   // read2 -> cat[:,256:384]
    bank_pass<3, 0><<<dim3(16, kB), 256, 0, stream>>>(p);
  }
  // ---- output projection (bias pre-initialized by gates_gemm init block) ----
  out_gemm<<<dim3(kO / 64, kCatW / 128), 256, 0, stream>>>(cat, out_W, out);

  (void)in_sizes; (void)n_in; (void)out_size; (void)ws_size;
}

// Round 4
// 490.449 us; speedup vs baseline: 1.6306x; 1.6306x over previous
//
#include <hip/hip_runtime.h>
#include <math.h>

namespace {

constexpr int kB = 64;
constexpr int kN = 4096;
constexpr int kM = 128;
constexpr int kH = 512;
constexpr int kE = 256;
constexpr int kO = 256;
constexpr int kGates = 4 * kH;       // 2048
constexpr int kCatW = 3 * kM + kH;   // 896  (read0|read1|read2|h)
constexpr int kPRow = 1600;          // padded 1572
constexpr int kWN = kB * kN;

__device__ __forceinline__ float sigm_(float x) { return 1.f / (1.f + expf(-x)); }
__device__ __forceinline__ float softplus_(float x) { return x > 20.f ? x : log1pf(expf(x)); }

// =============== K1: gates GEMM (K-internal) + misc init block ===============
__global__ __launch_bounds__(256) void gates_gemm(const float* __restrict__ x,
                                                  const float* __restrict__ W_ih,
                                                  const float* __restrict__ h_prev,
                                                  const float* __restrict__ W_hh,
                                                  float* __restrict__ gates,
                                                  const float* __restrict__ out_b,
                                                  float* __restrict__ out,
                                                  float* __restrict__ cat) {
  if (blockIdx.x == 32) {   // init block
    const int tid = threadIdx.x;
    for (int i = tid; i < kB * kO; i += 256) out[i] = out_b[i & (kO - 1)];
    for (int i = tid; i < kB * 384; i += 256) cat[(i / 384) * kCatW + (i % 384)] = 0.f;
    return;
  }
  __shared__ float As[64][68];
  __shared__ float Ws[64][68];
  const int tid = threadIdx.x;
  const int j0 = blockIdx.x * 64;
  const int b0 = (tid & 15) * 4;
  const int j4 = (tid >> 4) * 4;
  float acc[4][4] = {};
  for (int kc = 0; kc < 12; kc++) {
    const bool isx = kc < 4;
    const float* A = isx ? x : h_prev;
    const float* W = isx ? W_ih : W_hh;
    const int lda = isx ? kE : kH;
    const int k0 = (isx ? kc : (kc - 4)) * 64;
    __syncthreads();
#pragma unroll
    for (int i = 0; i < 4; i++) {
      int idx = tid + i * 256;
      int bb = idx >> 4;
      int kk = (idx & 15) * 4;
      float4 v = *(const float4*)(A + (size_t)bb * lda + k0 + kk);
      As[kk][bb] = v.x; As[kk + 1][bb] = v.y; As[kk + 2][bb] = v.z; As[kk + 3][bb] = v.w;
      float4 w = *(const float4*)(W + (size_t)(j0 + bb) * lda + k0 + kk);
      Ws[kk][bb] = w.x; Ws[kk + 1][bb] = w.y; Ws[kk + 2][bb] = w.z; Ws[kk + 3][bb] = w.w;
    }
    __syncthreads();
#pragma unroll 2
    for (int k = 0; k < 64; k++) {
      float4 av = *(const float4*)&As[k][b0];
      float4 wv = *(const float4*)&Ws[k][j4];
      float aa[4] = {av.x, av.y, av.z, av.w};
      float ww[4] = {wv.x, wv.y, wv.z, wv.w};
#pragma unroll
      for (int ii = 0; ii < 4; ii++)
#pragma unroll
        for (int jj = 0; jj < 4; jj++) acc[ii][jj] += aa[ii] * ww[jj];
    }
  }
#pragma unroll
  for (int ii = 0; ii < 4; ii++) {
    float4 st = make_float4(acc[ii][0], acc[ii][1], acc[ii][2], acc[ii][3]);
    *(float4*)&gates[(size_t)(b0 + ii) * kGates + j0 + j4] = st;
  }
}

// =============== LSTM nonlinearity ===============
__global__ __launch_bounds__(256) void lstm_nl(const float* __restrict__ gates,
                                               const float* __restrict__ b_ih,
                                               const float* __restrict__ b_hh,
                                               const float* __restrict__ c_prev,
                                               float* __restrict__ cat) {
  int idx = blockIdx.x * 256 + threadIdx.x;
  if (idx >= kB * kH) return;
  int b = idx >> 9;
  int hh = idx & (kH - 1);
  const float* g = gates + (size_t)b * kGates;
  float i_ = g[hh]          + b_ih[hh]          + b_hh[hh];
  float f_ = g[kH + hh]     + b_ih[kH + hh]     + b_hh[kH + hh];
  float g_ = g[2 * kH + hh] + b_ih[2 * kH + hh] + b_hh[2 * kH + hh];
  float o_ = g[3 * kH + hh] + b_ih[3 * kH + hh] + b_hh[3 * kH + hh];
  float c = sigm_(f_) * c_prev[idx] + sigm_(i_) * tanhf(g_);
  cat[(size_t)b * kCatW + 3 * kM + hh] = sigm_(o_) * tanhf(c);
}

// =============== K2: head projections GEMM ===============
__global__ __launch_bounds__(256) void proj_gemm(const float* __restrict__ cat,
                                                 const float* __restrict__ write_W,
                                                 const float* __restrict__ read_W,
                                                 float* __restrict__ praw) {
  __shared__ float As[64][68];
  __shared__ float Ws[64][68];
  const float* A = cat + 3 * kM;  // h, lda = kCatW
  const int tid = threadIdx.x;
  const int j0 = blockIdx.x * 64;
  const int b0 = (tid & 15) * 4;
  const int j4 = (tid >> 4) * 4;
  float acc[4][4] = {};
  for (int kc = 0; kc < 8; kc++) {
    const int k0 = kc * 64;
    __syncthreads();
#pragma unroll
    for (int i = 0; i < 4; i++) {
      int idx = tid + i * 256;
      int bb = idx >> 4;
      int kk = (idx & 15) * 4;
      float4 v = *(const float4*)(A + (size_t)bb * kCatW + k0 + kk);
      As[kk][bb] = v.x; As[kk + 1][bb] = v.y; As[kk + 2][bb] = v.z; As[kk + 3][bb] = v.w;
      int j = j0 + bb;
      float4 w = make_float4(0.f, 0.f, 0.f, 0.f);
      if (j < 1170)      w = *(const float4*)(write_W + (size_t)j * kH + k0 + kk);
      else if (j < 1572) w = *(const float4*)(read_W + (size_t)(j - 1170) * kH + k0 + kk);
      Ws[kk][bb] = w.x; Ws[kk + 1][bb] = w.y; Ws[kk + 2][bb] = w.z; Ws[kk + 3][bb] = w.w;
    }
    __syncthreads();
#pragma unroll 2
    for (int k = 0; k < 64; k++) {
      float4 av = *(const float4*)&As[k][b0];
      float4 wv = *(const float4*)&Ws[k][j4];
      float aa[4] = {av.x, av.y, av.z, av.w};
      float ww[4] = {wv.x, wv.y, wv.z, wv.w};
#pragma unroll
      for (int ii = 0; ii < 4; ii++)
#pragma unroll
        for (int jj = 0; jj < 4; jj++) acc[ii][jj] += aa[ii] * ww[jj];
    }
  }
  if (j0 + j4 < 1572) {
#pragma unroll
    for (int ii = 0; ii < 4; ii++) {
      float4 st = make_float4(acc[ii][0], acc[ii][1], acc[ii][2], acc[ii][3]);
      *(float4*)&praw[(size_t)(b0 + ii) * kPRow + j0 + j4] = st;
    }
  }
}

// =============== split head params + per-batch scalar dots ===============
__global__ __launch_bounds__(128) void split_params(const float* __restrict__ praw,
                                                    const float* __restrict__ write_b,
                                                    const float* __restrict__ read_b,
                                                    float* __restrict__ kwb, float* __restrict__ krb,
                                                    float* __restrict__ evb, float* __restrict__ avb,
                                                    float* __restrict__ scal,
                                                    float* __restrict__ sdot) {
  const int b = blockIdx.x;
  const int m = threadIdx.x;
  __shared__ float red[2];
  for (int i = 0; i < 3; i++) {  // write heads
    const float* p = praw + (size_t)b * kPRow + i * 390;
    const float* wb = write_b + i * 390;
    float kv = p[m] + wb[m];
    kwb[((size_t)i * kB + b) * kM + m] = kv;
    evb[((size_t)i * kB + b) * kM + m] = sigm_(p[134 + m] + wb[134 + m]);
    avb[((size_t)i * kB + b) * kM + m] = p[262 + m] + wb[262 + m];
    float sq = kv * kv;
#pragma unroll
    for (int mm = 1; mm < 64; mm <<= 1) sq += __shfl_xor(sq, mm, 64);
    __syncthreads();
    if ((m & 63) == 0) red[m >> 6] = sq;
    __syncthreads();
    if (m == 0) {
      float* s = scal + ((size_t)i * kB + b) * 8;
      s[0] = softplus_(p[128] + wb[128]);
      s[1] = sigm_(p[129] + wb[129]);
      s[2] = 1.f + softplus_(p[133] + wb[133]);
      float x0 = p[130] + wb[130], x1 = p[131] + wb[131], x2 = p[132] + wb[132];
      float mx = fmaxf(x0, fmaxf(x1, x2));
      float e0 = expf(x0 - mx), e1 = expf(x1 - mx), e2 = expf(x2 - mx);
      float si = 1.f / (e0 + e1 + e2);
      s[3] = e0 * si; s[4] = e1 * si; s[5] = e2 * si;
      s[6] = sqrtf(red[0] + red[1]);
    }
    __syncthreads();
  }
  for (int i = 0; i < 3; i++) {  // read heads
    const float* p = praw + (size_t)b * kPRow + 1170 + i * 134;
    const float* rb = read_b + i * 134;
    float kv = p[m] + rb[m];
    krb[((size_t)i * kB + b) * kM + m] = kv;
    float sq = kv * kv;
#pragma unroll
    for (int mm = 1; mm < 64; mm <<= 1) sq += __shfl_xor(sq, mm, 64);
    __syncthreads();
    if ((m & 63) == 0) red[m >> 6] = sq;
    __syncthreads();
    if (m == 0) {
      float* s = scal + ((size_t)(3 + i) * kB + b) * 8;
      s[0] = softplus_(p[128] + rb[128]);
      s[1] = sigm_(p[129] + rb[129]);
      s[2] = 1.f + softplus_(p[133] + rb[133]);
      float x0 = p[130] + rb[130], x1 = p[131] + rb[131], x2 = p[132] + rb[132];
      float mx = fmaxf(x0, fmaxf(x1, x2));
      float e0 = expf(x0 - mx), e1 = expf(x1 - mx), e2 = expf(x2 - mx);
      float si = 1.f / (e0 + e1 + e2);
      s[3] = e0 * si; s[4] = e1 * si; s[5] = e2 * si;
      s[6] = sqrtf(red[0] + red[1]);
    }
    __syncthreads();
  }
  // per-batch scalar dots: {a0.kr0, a0.kw1, a0.a0, a2.kr2, a2.a2}
  __syncthreads();
  if (m < 64) {
    const float* a0 = avb + ((size_t)0 * kB + b) * kM;
    const float* a2 = avb + ((size_t)2 * kB + b) * kM;
    const float* u[5] = {a0, a0, a0, a2, a2};
    const float* v[5] = {krb + ((size_t)0 * kB + b) * kM,
                         kwb + ((size_t)1 * kB + b) * kM,
                         a0,
                         krb + ((size_t)2 * kB + b) * kM,
                         a2};
#pragma unroll
    for (int d = 0; d < 5; d++) {
      float s = u[d][m] * v[d][m] + u[d][m + 64] * v[d][m + 64];
#pragma unroll
      for (int mm = 1; mm < 64; mm <<= 1) s += __shfl_xor(s, mm, 64);
      if (m == 0) sdot[b * 8 + d] = s;
    }
  }
}

// =============== Pass A: B0 moments ===============
// planes: 0:B.kw0 1:B.B 2:B.kr0 3:B.(e0kr0) 4:B.kw1 5:B.(e0kw1)
//         6:SumB2e0 7:SumB2e0^2 8:B.a0 9:B.(e0a0)
__global__ __launch_bounds__(256) void passA_k(const float* __restrict__ bank,
                                               const float* __restrict__ kwb,
                                               const float* __restrict__ krb,
                                               const float* __restrict__ evb,
                                               const float* __restrict__ avb,
                                               float* __restrict__ mA) {
  const int b = blockIdx.y, chunk = blockIdx.x;
  const int tid = threadIdx.x;
  const int lane = tid & 63, wv = tid >> 6, sub = lane >> 4, lm = lane & 15;
  const int m8 = lm * 8;
  float kw0r[8], kr0r[8], kw1r[8], a0r[8], e0r[8];
#pragma unroll
  for (int t = 0; t < 8; t++) {
    kw0r[t] = kwb[((size_t)0 * kB + b) * kM + m8 + t];
    kr0r[t] = krb[((size_t)0 * kB + b) * kM + m8 + t];
    kw1r[t] = kwb[((size_t)1 * kB + b) * kM + m8 + t];
    a0r[t]  = avb[((size_t)0 * kB + b) * kM + m8 + t];
    e0r[t]  = evb[((size_t)0 * kB + b) * kM + m8 + t];
  }
  const size_t bbase = (size_t)b * kN * kM;
  const size_t brow = (size_t)b * kN;
  for (int it = 0; it < 16; it++) {
    const int row = chunk * 256 + it * 16 + wv * 4 + sub;
    const float* rp = bank + bbase + (size_t)row * kM + m8;
    float4 u0 = *(const float4*)rp;
    float4 u1 = *(const float4*)(rp + 4);
    float v[8] = {u0.x, u0.y, u0.z, u0.w, u1.x, u1.y, u1.z, u1.w};
    float s[10] = {};
#pragma unroll
    for (int t = 0; t < 8; t++) {
      float be = v[t] * e0r[t];
      s[0] += v[t] * kw0r[t];
      s[1] += v[t] * v[t];
      s[2] += v[t] * kr0r[t];
      s[3] += be * kr0r[t];
      s[4] += v[t] * kw1r[t];
      s[5] += be * kw1r[t];
      s[6] += be * v[t];
      s[7] += be * be;
      s[8] += v[t] * a0r[t];
      s[9] += be * a0r[t];
    }
#pragma unroll
    for (int m = 1; m < 16; m <<= 1)
#pragma unroll
      for (int k = 0; k < 10; k++) s[k] += __shfl_xor(s[k], m, 64);
    if (lm == 0) {
#pragma unroll
      for (int k = 0; k < 10; k++) mA[(size_t)k * kWN + brow + row] = s[k];
    }
  }
}

// =============== addressing core: loc (raw scores) -> final weights in loc ===============
__device__ void addr_core(int tid, float* loc, const float* sc, const float* __restrict__ wp,
                          float* wb, float* red) {
  const float g = sc[1], r = sc[2];
  const float s0 = sc[3], s1 = sc[4], s2 = sc[5];
  const int lane = tid & 63, wid = tid >> 6;
  __syncthreads();
  float mx = -1e30f;
#pragma unroll
  for (int i = 0; i < 16; i++) mx = fmaxf(mx, loc[i]);
#pragma unroll
  for (int m = 1; m < 64; m <<= 1) mx = fmaxf(mx, __shfl_xor(mx, m, 64));
  if (lane == 0) red[wid] = mx;
  __syncthreads();
  mx = fmaxf(fmaxf(red[0], red[1]), fmaxf(red[2], red[3]));
  float sum = 0.f;
#pragma unroll
  for (int i = 0; i < 16; i++) { loc[i] = expf(loc[i] - mx); sum += loc[i]; }
#pragma unroll
  for (int m = 1; m < 64; m <<= 1) sum += __shfl_xor(sum, m, 64);
  __syncthreads();
  if (lane == 0) red[wid] = sum;
  __syncthreads();
  sum = red[0] + red[1] + red[2] + red[3];
  const float inv = 1.f / sum;
  const float omg = 1.f - g;
#pragma unroll
  for (int i = 0; i < 16; i++) {
    int n = tid + i * 256;
    wb[n] = loc[i] * inv + omg * wp[n];
  }
  __syncthreads();
  float ssum = 0.f;
#pragma unroll
  for (int i = 0; i < 16; i++) {
    int n = tid + i * 256;
    float sh = s0 * wb[(n + kN - 1) & (kN - 1)] + s1 * wb[n] + s2 * wb[(n + 1) & (kN - 1)];
    float y = powf(sh, r);
    loc[i] = y;
    ssum += y;
  }
#pragma unroll
  for (int m = 1; m < 64; m <<= 1) ssum += __shfl_xor(ssum, m, 64);
  __syncthreads();
  if (lane == 0) red[wid] = ssum;
  __syncthreads();
  ssum = red[0] + red[1] + red[2] + red[3];
  const float invs = 1.f / (ssum + 1e-8f);
#pragma unroll
  for (int i = 0; i < 16; i++) loc[i] *= invs;
}

// =============== A12: w0, wr0, w1 from pass-A moments (one block per b) ===============
__global__ __launch_bounds__(256) void a12_k(const float* __restrict__ mA,
                                             const float* __restrict__ scal,
                                             const float* __restrict__ sdot,
                                             const float* __restrict__ read_w_prev,
                                             const float* __restrict__ write_w_prev,
                                             float* __restrict__ wwv,
                                             float* __restrict__ wrv) {
  const int b = blockIdx.x;
  const int tid = threadIdx.x;
  __shared__ float wb[kN];
  __shared__ float red[4];
  const size_t brow = (size_t)b * kN;
  float loc[16], w0r[16], q1r[16];
  // phase 1: write head 0 on B0
  {
    const float* sc = scal + ((size_t)0 * kB + b) * 8;
    const float beta = sc[0], kn = sc[6];
#pragma unroll
    for (int i = 0; i < 16; i++) {
      size_t idx = brow + tid + i * 256;
      float d = mA[0 * (size_t)kWN + idx];
      float q = mA[1 * (size_t)kWN + idx];
      loc[i] = beta * d / fmaxf(sqrtf(fmaxf(q, 0.f)) * kn, 1e-8f);
    }
    addr_core(tid, loc, sc, write_w_prev + brow, wb, red);
#pragma unroll
    for (int i = 0; i < 16; i++) { wwv[brow + tid + i * 256] = loc[i]; w0r[i] = loc[i]; }
  }
  // phase 2: read head 0 on B1 (expanded)
  {
    const float* sc = scal + ((size_t)3 * kB + b) * 8;
    const float beta = sc[0], kn = sc[6];
    const float sa0kr0 = sdot[b * 8 + 0], sa0a0 = sdot[b * 8 + 2];
#pragma unroll
    for (int i = 0; i < 16; i++) {
      size_t idx = brow + tid + i * 256;
      float w0 = w0r[i], w0q = w0 * w0;
      float q1 = mA[1 * (size_t)kWN + idx]
               - 2.f * w0 * mA[6 * (size_t)kWN + idx]
               + w0q * mA[7 * (size_t)kWN + idx]
               + 2.f * w0 * mA[8 * (size_t)kWN + idx]
               - 2.f * w0q * mA[9 * (size_t)kWN + idx]
               + w0q * sa0a0;
      q1r[i] = q1;
      float d = mA[2 * (size_t)kWN + idx] - w0 * mA[3 * (size_t)kWN + idx] + w0 * sa0kr0;
      loc[i] = beta * d / fmaxf(sqrtf(fmaxf(q1, 0.f)) * kn, 1e-8f);
    }
    addr_core(tid, loc, sc, read_w_prev + brow, wb, red);
#pragma unroll
    for (int i = 0; i < 16; i++) wrv[brow + tid + i * 256] = loc[i];
  }
  // phase 3: write head 1 on B1 (expanded)
  {
    const float* sc = scal + ((size_t)1 * kB + b) * 8;
    const float beta = sc[0], kn = sc[6];
    const float sa0kw1 = sdot[b * 8 + 1];
#pragma unroll
    for (int i = 0; i < 16; i++) {
      size_t idx = brow + tid + i * 256;
      float w0 = w0r[i];
      float d = mA[4 * (size_t)kWN + idx] - w0 * mA[5 * (size_t)kWN + idx] + w0 * sa0kw1;
      loc[i] = beta * d / fmaxf(sqrtf(fmaxf(q1r[i], 0.f)) * kn, 1e-8f);
    }
    addr_core(tid, loc, sc, write_w_prev + kWN + brow, wb, red);
#pragma unroll
    for (int i = 0; i < 16; i++) wwv[kWN + brow + tid + i * 256] = loc[i];
  }
}

// =============== Pass B: chain(w0,w1), read0, B2 scores + B2 moments ===============
// planes: 0:B2.kr1 1:B2.kw2 2:B2.B2 3:B2.kr2 4:B2.(e2kr2) 5:SumB2^2e2 6:SumB2^2e2^2 7:B2.a2 8:B2.(e2a2)
__global__ __launch_bounds__(256) void passB_k(const float* __restrict__ bank,
                                               const float* __restrict__ wwv,
                                               const float* __restrict__ wrv,
                                               const float* __restrict__ kwb,
                                               const float* __restrict__ krb,
                                               const float* __restrict__ evb,
                                               const float* __restrict__ avb,
                                               float* __restrict__ cat,
                                               float* __restrict__ mB) {
  const int b = blockIdx.y, chunk = blockIdx.x;
  const int tid = threadIdx.x;
  const int lane = tid & 63, wv = tid >> 6, sub = lane >> 4, lm = lane & 15;
  const int m8 = lm * 8;
  float e0r[8], a0r[8], e1r[8], a1r[8], kr1r[8], kw2r[8], kr2r[8], e2r[8], a2r[8];
#pragma unroll
  for (int t = 0; t < 8; t++) {
    e0r[t]  = evb[((size_t)0 * kB + b) * kM + m8 + t];
    a0r[t]  = avb[((size_t)0 * kB + b) * kM + m8 + t];
    e1r[t]  = evb[((size_t)1 * kB + b) * kM + m8 + t];
    a1r[t]  = avb[((size_t)1 * kB + b) * kM + m8 + t];
    kr1r[t] = krb[((size_t)1 * kB + b) * kM + m8 + t];
    kw2r[t] = kwb[((size_t)2 * kB + b) * kM + m8 + t];
    kr2r[t] = krb[((size_t)2 * kB + b) * kM + m8 + t];
    e2r[t]  = evb[((size_t)2 * kB + b) * kM + m8 + t];
    a2r[t]  = avb[((size_t)2 * kB + b) * kM + m8 + t];
  }
  float racc[8] = {};
  __shared__ float rlds[kM];
  if (tid < kM) rlds[tid] = 0.f;
  const size_t bbase = (size_t)b * kN * kM;
  const size_t brow = (size_t)b * kN;
  for (int it = 0; it < 16; it++) {
    const int row = chunk * 256 + it * 16 + wv * 4 + sub;
    const float* rp = bank + bbase + (size_t)row * kM + m8;
    float4 u0 = *(const float4*)rp;
    float4 u1 = *(const float4*)(rp + 4);
    float v[8] = {u0.x, u0.y, u0.z, u0.w, u1.x, u1.y, u1.z, u1.w};
    const float w0 = wwv[brow + row];
    const float w1 = wwv[kWN + brow + row];
    const float wr0 = wrv[brow + row];
#pragma unroll
    for (int t = 0; t < 8; t++) {
      v[t] += w0 * (a0r[t] - e0r[t] * v[t]);        // -> B1
      racc[t] += wr0 * v[t];                         // read0 from B1
      v[t] += w1 * (a1r[t] - e1r[t] * v[t]);        // -> B2
    }
    float s[9] = {};
#pragma unroll
    for (int t = 0; t < 8; t++) {
      float ve = v[t] * e2r[t];
      s[0] += v[t] * kr1r[t];
      s[1] += v[t] * kw2r[t];
      s[2] += v[t] * v[t];
      s[3] += v[t] * kr2r[t];
      s[4] += ve * kr2r[t];
      s[5] += ve * v[t];
      s[6] += ve * ve;
      s[7] += v[t] * a2r[t];
      s[8] += ve * a2r[t];
    }
#pragma unroll
    for (int m = 1; m < 16; m <<= 1)
#pragma unroll
      for (int k = 0; k < 9; k++) s[k] += __shfl_xor(s[k], m, 64);
    if (lm == 0) {
#pragma unroll
      for (int k = 0; k < 9; k++) mB[(size_t)k * kWN + brow + row] = s[k];
    }
  }
  __syncthreads();
#pragma unroll
  for (int t = 0; t < 8; t++) {
    racc[t] += __shfl_xor(racc[t], 16, 64);
    racc[t] += __shfl_xor(racc[t], 32, 64);
  }
  if (sub == 0) {
#pragma unroll
    for (int t = 0; t < 8; t++) atomicAdd(&rlds[m8 + t], racc[t]);
  }
  __syncthreads();
  if (tid < kM) atomicAdd(&cat[(size_t)b * kCatW + tid], rlds[tid]);
}

// =============== A34: wr1, w2, wr2 from pass-B moments ===============
__global__ __launch_bounds__(256) void a34_k(const float* __restrict__ mB,
                                             const float* __restrict__ scal,
                                             const float* __restrict__ sdot,
                                             const float* __restrict__ read_w_prev,
                                             const float* __restrict__ write_w_prev,
                                             float* __restrict__ wwv,
                                             float* __restrict__ wrv) {
  const int b = blockIdx.x;
  const int tid = threadIdx.x;
  __shared__ float wb[kN];
  __shared__ float red[4];
  const size_t brow = (size_t)b * kN;
  float loc[16], w2r[16];
  // phase 1: read head 1 on B2 (direct)
  {
    const float* sc = scal + ((size_t)4 * kB + b) * 8;
    const float beta = sc[0], kn = sc[6];
#pragma unroll
    for (int i = 0; i < 16; i++) {
      size_t idx = brow + tid + i * 256;
      float d = mB[0 * (size_t)kWN + idx];
      float q = mB[2 * (size_t)kWN + idx];
      loc[i] = beta * d / fmaxf(sqrtf(fmaxf(q, 0.f)) * kn, 1e-8f);
    }
    addr_core(tid, loc, sc, read_w_prev + kWN + brow, wb, red);
#pragma unroll
    for (int i = 0; i < 16; i++) wrv[kWN + brow + tid + i * 256] = loc[i];
  }
  // phase 2: write head 2 on B2 (direct)
  {
    const float* sc = scal + ((size_t)2 * kB + b) * 8;
    const float beta = sc[0], kn = sc[6];
#pragma unroll
    for (int i = 0; i < 16; i++) {
      size_t idx = brow + tid + i * 256;
      float d = mB[1 * (size_t)kWN + idx];
      float q = mB[2 * (size_t)kWN + idx];
      loc[i] = beta * d / fmaxf(sqrtf(fmaxf(q, 0.f)) * kn, 1e-8f);
    }
    addr_core(tid, loc, sc, write_w_prev + 2 * kWN + brow, wb, red);
#pragma unroll
    for (int i = 0; i < 16; i++) { wwv[2 * (size_t)kWN + brow + tid + i * 256] = loc[i]; w2r[i] = loc[i]; }
  }
  // phase 3: read head 2 on B3 (expanded)
  {
    const float* sc = scal + ((size_t)5 * kB + b) * 8;
    const float beta = sc[0], kn = sc[6];
    const float sa2kr2 = sdot[b * 8 + 3], sa2a2 = sdot[b * 8 + 4];
#pragma unroll
    for (int i = 0; i < 16; i++) {
      size_t idx = brow + tid + i * 256;
      float w2 = w2r[i], w2q = w2 * w2;
      float q3 = mB[2 * (size_t)kWN + idx]
               - 2.f * w2 * mB[5 * (size_t)kWN + idx]
               + w2q * mB[6 * (size_t)kWN + idx]
               + 2.f * w2 * mB[7 * (size_t)kWN + idx]
               - 2.f * w2q * mB[8 * (size_t)kWN + idx]
               + w2q * sa2a2;
      float d = mB[3 * (size_t)kWN + idx] - w2 * mB[4 * (size_t)kWN + idx] + w2 * sa2kr2;
      loc[i] = beta * d / fmaxf(sqrtf(fmaxf(q3, 0.f)) * kn, 1e-8f);
    }
    addr_core(tid, loc, sc, read_w_prev + 2 * kWN + brow, wb, red);
#pragma unroll
    for (int i = 0; i < 16; i++) wrv[2 * (size_t)kWN + brow + tid + i * 256] = loc[i];
  }
}

// =============== Pass C: chain(w0,w1,w2), read1 from B2, read2 from B3 ===============
__global__ __launch_bounds__(256) void passC_k(const float* __restrict__ bank,
                                               const float* __restrict__ wwv,
                                               const float* __restrict__ wrv,
                                               const float* __restrict__ evb,
                                               const float* __restrict__ avb,
                                               float* __restrict__ cat) {
  const int b = blockIdx.y, chunk = blockIdx.x;
  const int tid = threadIdx.x;
  const int lane = tid & 63, wv = tid >> 6, sub = lane >> 4, lm = lane & 15;
  const int m8 = lm * 8;
  float e_r[3][8], a_r[3][8];
#pragma unroll
  for (int j = 0; j < 3; j++)
#pragma unroll
    for (int t = 0; t < 8; t++) {
      e_r[j][t] = evb[((size_t)j * kB + b) * kM + m8 + t];
      a_r[j][t] = avb[((size_t)j * kB + b) * kM + m8 + t];
    }
  float racc1[8] = {}, racc2[8] = {};
  __shared__ float rlds[2][kM];
  if (tid < kM) { rlds[0][tid] = 0.f; rlds[1][tid] = 0.f; }
  const size_t bbase = (size_t)b * kN * kM;
  const size_t brow = (size_t)b * kN;
  for (int it = 0; it < 16; it++) {
    const int row = chunk * 256 + it * 16 + wv * 4 + sub;
    const float* rp = bank + bbase + (size_t)row * kM + m8;
    float4 u0 = *(const float4*)rp;
    float4 u1 = *(const float4*)(rp + 4);
    float v[8] = {u0.x, u0.y, u0.z, u0.w, u1.x, u1.y, u1.z, u1.w};
    const float w0 = wwv[brow + row];
    const float w1 = wwv[kWN + brow + row];
    const float w2 = wwv[2 * (size_t)kWN + brow + row];
    const float wr1 = wrv[kWN + brow + row];
    const float wr2 = wrv[2 * (size_t)kWN + brow + row];
#pragma unroll
    for (int t = 0; t < 8; t++) {
      v[t] += w0 * (a_r[0][t] - e_r[0][t] * v[t]);  // B1
      v[t] += w1 * (a_r[1][t] - e_r[1][t] * v[t]);  // B2
      racc1[t] += wr1 * v[t];
      v[t] += w2 * (a_r[2][t] - e_r[2][t] * v[t]);  // B3
      racc2[t] += wr2 * v[t];
    }
  }
  __syncthreads();
#pragma unroll
  for (int t = 0; t < 8; t++) {
    racc1[t] += __shfl_xor(racc1[t], 16, 64);
    racc1[t] += __shfl_xor(racc1[t], 32, 64);
    racc2[t] += __shfl_xor(racc2[t], 16, 64);
    racc2[t] += __shfl_xor(racc2[t], 32, 64);
  }
  if (sub == 0) {
#pragma unroll
    for (int t = 0; t < 8; t++) {
      atomicAdd(&rlds[0][m8 + t], racc1[t]);
      atomicAdd(&rlds[1][m8 + t], racc2[t]);
    }
  }
  __syncthreads();
  if (tid < kM) {
    atomicAdd(&cat[(size_t)b * kCatW + kM + tid], rlds[0][tid]);
    atomicAdd(&cat[(size_t)b * kCatW + 2 * kM + tid], rlds[1][tid]);
  }
}

// =============== out GEMM: split-K atomic (out pre-initialized with bias) ===============
__global__ __launch_bounds__(256) void out_gemm(const float* __restrict__ A,
                                                const float* __restrict__ W,
                                                float* __restrict__ C) {
  __shared__ float As[64][68];
  __shared__ float Ws[64][68];
  const int tid = threadIdx.x;
  const int j0 = blockIdx.x * 64;
  const int b0 = (tid & 15) * 4;
  const int j4 = (tid >> 4) * 4;
  float acc[4][4] = {};
  for (int kc = 0; kc < 2; kc++) {
    const int k0 = blockIdx.y * 128 + kc * 64;
    __syncthreads();
#pragma unroll
    for (int i = 0; i < 4; i++) {
      int idx = tid + i * 256;
      int bb = idx >> 4;
      int kk = (idx & 15) * 4;
      float4 v = *(const float4*)(A + (size_t)bb * kCatW + k0 + kk);
      As[kk][bb] = v.x; As[kk + 1][bb] = v.y; As[kk + 2][bb] = v.z; As[kk + 3][bb] = v.w;
      float4 w = *(const float4*)(W + (size_t)(j0 + bb) * kCatW + k0 + kk);
      Ws[kk][bb] = w.x; Ws[kk + 1][bb] = w.y; Ws[kk + 2][bb] = w.z; Ws[kk + 3][bb] = w.w;
    }
    __syncthreads();
#pragma unroll 2
    for (int k = 0; k < 64; k++) {
      float4 av = *(const float4*)&As[k][b0];
      float4 wv = *(const float4*)&Ws[k][j4];
      float aa[4] = {av.x, av.y, av.z, av.w};
      float ww[4] = {wv.x, wv.y, wv.z, wv.w};
#pragma unroll
      for (int ii = 0; ii < 4; ii++)
#pragma unroll
        for (int jj = 0; jj < 4; jj++) acc[ii][jj] += aa[ii] * ww[jj];
    }
  }
#pragma unroll
  for (int ii = 0; ii < 4; ii++)
#pragma unroll
    for (int jj = 0; jj < 4; jj++)
      atomicAdd(&C[(size_t)(b0 + ii) * kO + j0 + j4 + jj], acc[ii][jj]);
}

}  // namespace

extern "C" void kernel_launch(void* const* d_in, const int* in_sizes, int n_in,
                              void* d_out, int out_size, void* d_ws, size_t ws_size,
                              hipStream_t stream) {
  const float* x            = (const float*)d_in[0];
  const float* h_prev       = (const float*)d_in[1];
  const float* c_prev       = (const float*)d_in[2];
  const float* bank         = (const float*)d_in[3];
  const float* read_w_prev  = (const float*)d_in[4];
  const float* write_w_prev = (const float*)d_in[5];
  const float* W_ih         = (const float*)d_in[6];
  const float* W_hh         = (const float*)d_in[7];
  const float* b_ih         = (const float*)d_in[8];
  const float* b_hh         = (const float*)d_in[9];
  const float* read_W       = (const float*)d_in[10];
  const float* read_b       = (const float*)d_in[11];
  const float* write_W      = (const float*)d_in[12];
  const float* write_b      = (const float*)d_in[13];
  const float* out_W        = (const float*)d_in[14];
  const float* out_b        = (const float*)d_in[15];
  float* out = (float*)d_out;

  float* ws    = (float*)d_ws;
  float* gates = ws;                         // 64*2048
  float* praw  = gates + kB * kGates;        // 64*1600
  float* cat   = praw + kB * kPRow;          // 64*896
  float* kwb   = cat + kB * kCatW;           // 3*64*128
  float* krb   = kwb + 3 * kB * kM;
  float* evb   = krb + 3 * kB * kM;
  float* avb   = evb + 3 * kB * kM;
  float* scal  = avb + 3 * kB * kM;          // 6*64*8
  float* sdot  = scal + 6 * kB * 8;          // 64*8
  float* wwv   = sdot + kB * 8;              // 3 planes (B,N)
  float* wrv   = wwv + 3 * kWN;              // 3 planes
  float* mA    = wrv + 3 * kWN;              // 10 planes
  float* mB    = mA + 10 * (size_t)kWN;      // 9 planes

  gates_gemm<<<33, 256, 0, stream>>>(x, W_ih, h_prev, W_hh, gates, out_b, out, cat);
  lstm_nl<<<(kB * kH) / 256, 256, 0, stream>>>(gates, b_ih, b_hh, c_prev, cat);
  proj_gemm<<<25, 256, 0, stream>>>(cat, write_W, read_W, praw);
  split_params<<<64, 128, 0, stream>>>(praw, write_b, read_b, kwb, krb, evb, avb, scal, sdot);

  passA_k<<<dim3(16, kB), 256, 0, stream>>>(bank, kwb, krb, evb, avb, mA);
  a12_k<<<64, 256, 0, stream>>>(mA, scal, sdot, read_w_prev, write_w_prev, wwv, wrv);
  passB_k<<<dim3(16, kB), 256, 0, stream>>>(bank, wwv, wrv, kwb, krb, evb, avb, cat, mB);
  a34_k<<<64, 256, 0, stream>>>(mB, scal, sdot, read_w_prev, write_w_prev, wwv, wrv);
  passC_k<<<dim3(16, kB), 256, 0, stream>>>(bank, wwv, wrv, evb, avb, cat);
  out_gemm<<<dim3(kO / 64, kCatW / 128), 256, 0, stream>>>(cat, out_W, out);

  (void)in_sizes; (void)n_in; (void)out_size; (void)ws_size;
}

// Round 5
// 445.225 us; speedup vs baseline: 1.7963x; 1.1016x over previous
//
#include <hip/hip_runtime.h>
#include <math.h>

namespace {

constexpr int kB = 64;
constexpr int kN = 4096;
constexpr int kM = 128;
constexpr int kH = 512;
constexpr int kE = 256;
constexpr int kO = 256;
constexpr int kGates = 4 * kH;       // 2048
constexpr int kCatW = 3 * kM + kH;   // 896  (read0|read1|read2|h)
constexpr int kPRow = 1600;          // padded 1572
constexpr int kWN = kB * kN;
constexpr float kLog2e = 1.4426950408889634f;

__device__ __forceinline__ float sigm_(float x) { return 1.f / (1.f + expf(-x)); }
__device__ __forceinline__ float softplus_(float x) { return x > 20.f ? x : log1pf(expf(x)); }

// =============== K1: gates GEMM (K-internal) + misc init block ===============
__global__ __launch_bounds__(256) void gates_gemm(const float* __restrict__ x,
                                                  const float* __restrict__ W_ih,
                                                  const float* __restrict__ h_prev,
                                                  const float* __restrict__ W_hh,
                                                  float* __restrict__ gates,
                                                  const float* __restrict__ out_b,
                                                  float* __restrict__ out,
                                                  float* __restrict__ cat) {
  if (blockIdx.x == 32) {   // init block
    const int tid = threadIdx.x;
    for (int i = tid; i < kB * kO; i += 256) out[i] = out_b[i & (kO - 1)];
    for (int i = tid; i < kB * 384; i += 256) cat[(i / 384) * kCatW + (i % 384)] = 0.f;
    return;
  }
  __shared__ float As[64][68];
  __shared__ float Ws[64][68];
  const int tid = threadIdx.x;
  const int j0 = blockIdx.x * 64;
  const int b0 = (tid & 15) * 4;
  const int j4 = (tid >> 4) * 4;
  float acc[4][4] = {};
  for (int kc = 0; kc < 12; kc++) {
    const bool isx = kc < 4;
    const float* A = isx ? x : h_prev;
    const float* W = isx ? W_ih : W_hh;
    const int lda = isx ? kE : kH;
    const int k0 = (isx ? kc : (kc - 4)) * 64;
    __syncthreads();
#pragma unroll
    for (int i = 0; i < 4; i++) {
      int idx = tid + i * 256;
      int bb = idx >> 4;
      int kk = (idx & 15) * 4;
      float4 v = *(const float4*)(A + (size_t)bb * lda + k0 + kk);
      As[kk][bb] = v.x; As[kk + 1][bb] = v.y; As[kk + 2][bb] = v.z; As[kk + 3][bb] = v.w;
      float4 w = *(const float4*)(W + (size_t)(j0 + bb) * lda + k0 + kk);
      Ws[kk][bb] = w.x; Ws[kk + 1][bb] = w.y; Ws[kk + 2][bb] = w.z; Ws[kk + 3][bb] = w.w;
    }
    __syncthreads();
#pragma unroll 2
    for (int k = 0; k < 64; k++) {
      float4 av = *(const float4*)&As[k][b0];
      float4 wv = *(const float4*)&Ws[k][j4];
      float aa[4] = {av.x, av.y, av.z, av.w};
      float ww[4] = {wv.x, wv.y, wv.z, wv.w};
#pragma unroll
      for (int ii = 0; ii < 4; ii++)
#pragma unroll
        for (int jj = 0; jj < 4; jj++) acc[ii][jj] += aa[ii] * ww[jj];
    }
  }
#pragma unroll
  for (int ii = 0; ii < 4; ii++) {
    float4 st = make_float4(acc[ii][0], acc[ii][1], acc[ii][2], acc[ii][3]);
    *(float4*)&gates[(size_t)(b0 + ii) * kGates + j0 + j4] = st;
  }
}

// =============== LSTM nonlinearity ===============
__global__ __launch_bounds__(256) void lstm_nl(const float* __restrict__ gates,
                                               const float* __restrict__ b_ih,
                                               const float* __restrict__ b_hh,
                                               const float* __restrict__ c_prev,
                                               float* __restrict__ cat) {
  int idx = blockIdx.x * 256 + threadIdx.x;
  if (idx >= kB * kH) return;
  int b = idx >> 9;
  int hh = idx & (kH - 1);
  const float* g = gates + (size_t)b * kGates;
  float i_ = g[hh]          + b_ih[hh]          + b_hh[hh];
  float f_ = g[kH + hh]     + b_ih[kH + hh]     + b_hh[kH + hh];
  float g_ = g[2 * kH + hh] + b_ih[2 * kH + hh] + b_hh[2 * kH + hh];
  float o_ = g[3 * kH + hh] + b_ih[3 * kH + hh] + b_hh[3 * kH + hh];
  float c = sigm_(f_) * c_prev[idx] + sigm_(i_) * tanhf(g_);
  cat[(size_t)b * kCatW + 3 * kM + hh] = sigm_(o_) * tanhf(c);
}

// =============== K2: head projections GEMM ===============
__global__ __launch_bounds__(256) void proj_gemm(const float* __restrict__ cat,
                                                 const float* __restrict__ write_W,
                                                 const float* __restrict__ read_W,
                                                 float* __restrict__ praw) {
  __shared__ float As[64][68];
  __shared__ float Ws[64][68];
  const float* A = cat + 3 * kM;  // h, lda = kCatW
  const int tid = threadIdx.x;
  const int j0 = blockIdx.x * 64;
  const int b0 = (tid & 15) * 4;
  const int j4 = (tid >> 4) * 4;
  float acc[4][4] = {};
  for (int kc = 0; kc < 8; kc++) {
    const int k0 = kc * 64;
    __syncthreads();
#pragma unroll
    for (int i = 0; i < 4; i++) {
      int idx = tid + i * 256;
      int bb = idx >> 4;
      int kk = (idx & 15) * 4;
      float4 v = *(const float4*)(A + (size_t)bb * kCatW + k0 + kk);
      As[kk][bb] = v.x; As[kk + 1][bb] = v.y; As[kk + 2][bb] = v.z; As[kk + 3][bb] = v.w;
      int j = j0 + bb;
      float4 w = make_float4(0.f, 0.f, 0.f, 0.f);
      if (j < 1170)      w = *(const float4*)(write_W + (size_t)j * kH + k0 + kk);
      else if (j < 1572) w = *(const float4*)(read_W + (size_t)(j - 1170) * kH + k0 + kk);
      Ws[kk][bb] = w.x; Ws[kk + 1][bb] = w.y; Ws[kk + 2][bb] = w.z; Ws[kk + 3][bb] = w.w;
    }
    __syncthreads();
#pragma unroll 2
    for (int k = 0; k < 64; k++) {
      float4 av = *(const float4*)&As[k][b0];
      float4 wv = *(const float4*)&Ws[k][j4];
      float aa[4] = {av.x, av.y, av.z, av.w};
      float ww[4] = {wv.x, wv.y, wv.z, wv.w};
#pragma unroll
      for (int ii = 0; ii < 4; ii++)
#pragma unroll
        for (int jj = 0; jj < 4; jj++) acc[ii][jj] += aa[ii] * ww[jj];
    }
  }
  if (j0 + j4 < 1572) {
#pragma unroll
    for (int ii = 0; ii < 4; ii++) {
      float4 st = make_float4(acc[ii][0], acc[ii][1], acc[ii][2], acc[ii][3]);
      *(float4*)&praw[(size_t)(b0 + ii) * kPRow + j0 + j4] = st;
    }
  }
}

// =============== split head params + per-batch scalar dots ===============
__global__ __launch_bounds__(128) void split_params(const float* __restrict__ praw,
                                                    const float* __restrict__ write_b,
                                                    const float* __restrict__ read_b,
                                                    float* __restrict__ kwb, float* __restrict__ krb,
                                                    float* __restrict__ evb, float* __restrict__ avb,
                                                    float* __restrict__ scal,
                                                    float* __restrict__ sdot) {
  const int b = blockIdx.x;
  const int m = threadIdx.x;
  __shared__ float red[2];
  for (int i = 0; i < 3; i++) {  // write heads
    const float* p = praw + (size_t)b * kPRow + i * 390;
    const float* wb = write_b + i * 390;
    float kv = p[m] + wb[m];
    kwb[((size_t)i * kB + b) * kM + m] = kv;
    evb[((size_t)i * kB + b) * kM + m] = sigm_(p[134 + m] + wb[134 + m]);
    avb[((size_t)i * kB + b) * kM + m] = p[262 + m] + wb[262 + m];
    float sq = kv * kv;
#pragma unroll
    for (int mm = 1; mm < 64; mm <<= 1) sq += __shfl_xor(sq, mm, 64);
    __syncthreads();
    if ((m & 63) == 0) red[m >> 6] = sq;
    __syncthreads();
    if (m == 0) {
      float* s = scal + ((size_t)i * kB + b) * 8;
      s[0] = softplus_(p[128] + wb[128]);
      s[1] = sigm_(p[129] + wb[129]);
      s[2] = 1.f + softplus_(p[133] + wb[133]);
      float x0 = p[130] + wb[130], x1 = p[131] + wb[131], x2 = p[132] + wb[132];
      float mx = fmaxf(x0, fmaxf(x1, x2));
      float e0 = expf(x0 - mx), e1 = expf(x1 - mx), e2 = expf(x2 - mx);
      float si = 1.f / (e0 + e1 + e2);
      s[3] = e0 * si; s[4] = e1 * si; s[5] = e2 * si;
      s[6] = sqrtf(red[0] + red[1]);
    }
    __syncthreads();
  }
  for (int i = 0; i < 3; i++) {  // read heads
    const float* p = praw + (size_t)b * kPRow + 1170 + i * 134;
    const float* rb = read_b + i * 134;
    float kv = p[m] + rb[m];
    krb[((size_t)i * kB + b) * kM + m] = kv;
    float sq = kv * kv;
#pragma unroll
    for (int mm = 1; mm < 64; mm <<= 1) sq += __shfl_xor(sq, mm, 64);
    __syncthreads();
    if ((m & 63) == 0) red[m >> 6] = sq;
    __syncthreads();
    if (m == 0) {
      float* s = scal + ((size_t)(3 + i) * kB + b) * 8;
      s[0] = softplus_(p[128] + rb[128]);
      s[1] = sigm_(p[129] + rb[129]);
      s[2] = 1.f + softplus_(p[133] + rb[133]);
      float x0 = p[130] + rb[130], x1 = p[131] + rb[131], x2 = p[132] + rb[132];
      float mx = fmaxf(x0, fmaxf(x1, x2));
      float e0 = expf(x0 - mx), e1 = expf(x1 - mx), e2 = expf(x2 - mx);
      float si = 1.f / (e0 + e1 + e2);
      s[3] = e0 * si; s[4] = e1 * si; s[5] = e2 * si;
      s[6] = sqrtf(red[0] + red[1]);
    }
    __syncthreads();
  }
  // per-batch scalar dots: {a0.kr0, a0.kw1, a0.a0, a2.kr2, a2.a2}
  __syncthreads();
  if (m < 64) {
    const float* a0 = avb + ((size_t)0 * kB + b) * kM;
    const float* a2 = avb + ((size_t)2 * kB + b) * kM;
    const float* u[5] = {a0, a0, a0, a2, a2};
    const float* v[5] = {krb + ((size_t)0 * kB + b) * kM,
                         kwb + ((size_t)1 * kB + b) * kM,
                         a0,
                         krb + ((size_t)2 * kB + b) * kM,
                         a2};
#pragma unroll
    for (int d = 0; d < 5; d++) {
      float s = u[d][m] * v[d][m] + u[d][m + 64] * v[d][m + 64];
#pragma unroll
      for (int mm = 1; mm < 64; mm <<= 1) s += __shfl_xor(s, mm, 64);
      if (m == 0) sdot[b * 8 + d] = s;
    }
  }
}

// =============== Pass A: B0 moments (prefetched streaming) ===============
// planes: 0:B.kw0 1:B.B 2:B.kr0 3:B.(e0kr0) 4:B.kw1 5:B.(e0kw1)
//         6:SumB2e0 7:SumB2e0^2 8:B.a0 9:B.(e0a0)
__global__ __launch_bounds__(256, 4) void passA_k(const float* __restrict__ bank,
                                                  const float* __restrict__ kwb,
                                                  const float* __restrict__ krb,
                                                  const float* __restrict__ evb,
                                                  const float* __restrict__ avb,
                                                  float* __restrict__ mA) {
  const int b = blockIdx.y, chunk = blockIdx.x;
  const int tid = threadIdx.x;
  const int lane = tid & 63, wv = tid >> 6, sub = lane >> 4, lm = lane & 15;
  const int m8 = lm * 8;
  float kw0r[8], kr0r[8], kw1r[8], a0r[8], e0r[8];
#pragma unroll
  for (int t = 0; t < 8; t++) {
    kw0r[t] = kwb[((size_t)0 * kB + b) * kM + m8 + t];
    kr0r[t] = krb[((size_t)0 * kB + b) * kM + m8 + t];
    kw1r[t] = kwb[((size_t)1 * kB + b) * kM + m8 + t];
    a0r[t]  = avb[((size_t)0 * kB + b) * kM + m8 + t];
    e0r[t]  = evb[((size_t)0 * kB + b) * kM + m8 + t];
  }
  const size_t bbase = (size_t)b * kN * kM;
  const size_t brow = (size_t)b * kN;
  const int row0 = chunk * 256 + wv * 4 + sub;
  const float* rp = bank + bbase + (size_t)row0 * kM + m8;
  float4 c0 = *(const float4*)rp;
  float4 c1 = *(const float4*)(rp + 4);
  for (int it = 0; it < 16; it++) {
    float v[8] = {c0.x, c0.y, c0.z, c0.w, c1.x, c1.y, c1.z, c1.w};
    if (it < 15) {
      const float* np = bank + bbase + (size_t)(row0 + (it + 1) * 16) * kM + m8;
      c0 = *(const float4*)np;
      c1 = *(const float4*)(np + 4);
    }
    const int row = row0 + it * 16;
    float s[10] = {};
#pragma unroll
    for (int t = 0; t < 8; t++) {
      float be = v[t] * e0r[t];
      s[0] += v[t] * kw0r[t];
      s[1] += v[t] * v[t];
      s[2] += v[t] * kr0r[t];
      s[3] += be * kr0r[t];
      s[4] += v[t] * kw1r[t];
      s[5] += be * kw1r[t];
      s[6] += be * v[t];
      s[7] += be * be;
      s[8] += v[t] * a0r[t];
      s[9] += be * a0r[t];
    }
#pragma unroll
    for (int m = 1; m < 16; m <<= 1)
#pragma unroll
      for (int k = 0; k < 10; k++) s[k] += __shfl_xor(s[k], m, 64);
    if (lm == 0) {
#pragma unroll
      for (int k = 0; k < 10; k++) mA[(size_t)k * kWN + brow + row] = s[k];
    }
  }
}

// ===== addressing core (1024 threads, 4 elems/thread): raw scores in loc -> final weights in loc =====
__device__ void addr_core4(int tid, float* loc, const float* sc, const float* __restrict__ wp,
                           float* wb, float* red) {
  const float g = sc[1], r = sc[2];
  const float s0 = sc[3], s1c = sc[4], s2 = sc[5];
  const int lane = tid & 63, wid = tid >> 6;  // wid 0..15
  __syncthreads();
  float mx = fmaxf(fmaxf(loc[0], loc[1]), fmaxf(loc[2], loc[3]));
#pragma unroll
  for (int m = 1; m < 64; m <<= 1) mx = fmaxf(mx, __shfl_xor(mx, m, 64));
  if (lane == 0) red[wid] = mx;
  __syncthreads();
  mx = red[0];
#pragma unroll
  for (int k = 1; k < 16; k++) mx = fmaxf(mx, red[k]);
  float sum = 0.f;
#pragma unroll
  for (int i = 0; i < 4; i++) { loc[i] = exp2f((loc[i] - mx) * kLog2e); sum += loc[i]; }
#pragma unroll
  for (int m = 1; m < 64; m <<= 1) sum += __shfl_xor(sum, m, 64);
  __syncthreads();
  if (lane == 0) red[wid] = sum;
  __syncthreads();
  sum = red[0];
#pragma unroll
  for (int k = 1; k < 16; k++) sum += red[k];
  const float inv = 1.f / sum;
  const float omg = 1.f - g;
#pragma unroll
  for (int i = 0; i < 4; i++) {
    int n = tid + i * 1024;
    wb[n] = loc[i] * inv + omg * wp[n];
  }
  __syncthreads();
  float ssum = 0.f;
#pragma unroll
  for (int i = 0; i < 4; i++) {
    int n = tid + i * 1024;
    float sh = s0 * wb[(n + kN - 1) & (kN - 1)] + s1c * wb[n] + s2 * wb[(n + 1) & (kN - 1)];
    float y = (sh > 0.f) ? exp2f(r * log2f(sh)) : 0.f;
    loc[i] = y;
    ssum += y;
  }
#pragma unroll
  for (int m = 1; m < 64; m <<= 1) ssum += __shfl_xor(ssum, m, 64);
  __syncthreads();
  if (lane == 0) red[wid] = ssum;
  __syncthreads();
  ssum = red[0];
#pragma unroll
  for (int k = 1; k < 16; k++) ssum += red[k];
  const float invs = 1.f / (ssum + 1e-8f);
#pragma unroll
  for (int i = 0; i < 4; i++) loc[i] *= invs;
  __syncthreads();
}

// =============== A12: w0, wr0, w1 from pass-A moments (one block per b, 1024 thr) ===============
__global__ __launch_bounds__(1024) void a12_k(const float* __restrict__ mA,
                                              const float* __restrict__ scal,
                                              const float* __restrict__ sdot,
                                              const float* __restrict__ read_w_prev,
                                              const float* __restrict__ write_w_prev,
                                              float* __restrict__ wwv,
                                              float* __restrict__ wrv) {
  const int b = blockIdx.x;
  const int tid = threadIdx.x;
  __shared__ float wb[kN];
  __shared__ float red[16];
  const size_t brow = (size_t)b * kN;
  float loc[4], w0r[4], q1r[4];
  // phase 1: write head 0 on B0
  {
    const float* sc = scal + ((size_t)0 * kB + b) * 8;
    const float beta = sc[0], kn = sc[6];
#pragma unroll
    for (int i = 0; i < 4; i++) {
      size_t idx = brow + tid + i * 1024;
      float d = mA[0 * (size_t)kWN + idx];
      float q = mA[1 * (size_t)kWN + idx];
      loc[i] = beta * d / fmaxf(sqrtf(fmaxf(q, 0.f)) * kn, 1e-8f);
    }
    addr_core4(tid, loc, sc, write_w_prev + brow, wb, red);
#pragma unroll
    for (int i = 0; i < 4; i++) { wwv[brow + tid + i * 1024] = loc[i]; w0r[i] = loc[i]; }
  }
  // phase 2: read head 0 on B1 (expanded)
  {
    const float* sc = scal + ((size_t)3 * kB + b) * 8;
    const float beta = sc[0], kn = sc[6];
    const float sa0kr0 = sdot[b * 8 + 0], sa0a0 = sdot[b * 8 + 2];
#pragma unroll
    for (int i = 0; i < 4; i++) {
      size_t idx = brow + tid + i * 1024;
      float w0 = w0r[i], w0q = w0 * w0;
      float q1 = mA[1 * (size_t)kWN + idx]
               - 2.f * w0 * mA[6 * (size_t)kWN + idx]
               + w0q * mA[7 * (size_t)kWN + idx]
               + 2.f * w0 * mA[8 * (size_t)kWN + idx]
               - 2.f * w0q * mA[9 * (size_t)kWN + idx]
               + w0q * sa0a0;
      q1r[i] = q1;
      float d = mA[2 * (size_t)kWN + idx] - w0 * mA[3 * (size_t)kWN + idx] + w0 * sa0kr0;
      loc[i] = beta * d / fmaxf(sqrtf(fmaxf(q1, 0.f)) * kn, 1e-8f);
    }
    addr_core4(tid, loc, sc, read_w_prev + brow, wb, red);
#pragma unroll
    for (int i = 0; i < 4; i++) wrv[brow + tid + i * 1024] = loc[i];
  }
  // phase 3: write head 1 on B1 (expanded)
  {
    const float* sc = scal + ((size_t)1 * kB + b) * 8;
    const float beta = sc[0], kn = sc[6];
    const float sa0kw1 = sdot[b * 8 + 1];
#pragma unroll
    for (int i = 0; i < 4; i++) {
      size_t idx = brow + tid + i * 1024;
      float w0 = w0r[i];
      float d = mA[4 * (size_t)kWN + idx] - w0 * mA[5 * (size_t)kWN + idx] + w0 * sa0kw1;
      loc[i] = beta * d / fmaxf(sqrtf(fmaxf(q1r[i], 0.f)) * kn, 1e-8f);
    }
    addr_core4(tid, loc, sc, write_w_prev + kWN + brow, wb, red);
#pragma unroll
    for (int i = 0; i < 4; i++) wwv[kWN + brow + tid + i * 1024] = loc[i];
  }
}

// =============== Pass B: chain(w0,w1), read0, B2 scores + B2 moments ===============
// planes: 0:B2.kr1 1:B2.kw2 2:B2.B2 3:B2.kr2 4:B2.(e2kr2) 5:SumB2^2e2 6:SumB2^2e2^2 7:B2.a2 8:B2.(e2a2)
__global__ __launch_bounds__(256, 4) void passB_k(const float* __restrict__ bank,
                                                  const float* __restrict__ wwv,
                                                  const float* __restrict__ wrv,
                                                  const float* __restrict__ kwb,
                                                  const float* __restrict__ krb,
                                                  const float* __restrict__ evb,
                                                  const float* __restrict__ avb,
                                                  float* __restrict__ cat,
                                                  float* __restrict__ mB) {
  const int b = blockIdx.y, chunk = blockIdx.x;
  const int tid = threadIdx.x;
  const int lane = tid & 63, wv = tid >> 6, sub = lane >> 4, lm = lane & 15;
  const int m8 = lm * 8;
  float e0r[8], a0r[8], e1r[8], a1r[8], kr1r[8], kw2r[8], kr2r[8], e2r[8], a2r[8];
#pragma unroll
  for (int t = 0; t < 8; t++) {
    e0r[t]  = evb[((size_t)0 * kB + b) * kM + m8 + t];
    a0r[t]  = avb[((size_t)0 * kB + b) * kM + m8 + t];
    e1r[t]  = evb[((size_t)1 * kB + b) * kM + m8 + t];
    a1r[t]  = avb[((size_t)1 * kB + b) * kM + m8 + t];
    kr1r[t] = krb[((size_t)1 * kB + b) * kM + m8 + t];
    kw2r[t] = kwb[((size_t)2 * kB + b) * kM + m8 + t];
    kr2r[t] = krb[((size_t)2 * kB + b) * kM + m8 + t];
    e2r[t]  = evb[((size_t)2 * kB + b) * kM + m8 + t];
    a2r[t]  = avb[((size_t)2 * kB + b) * kM + m8 + t];
  }
  float racc[8] = {};
  __shared__ float rlds[kM];
  if (tid < kM) rlds[tid] = 0.f;
  const size_t bbase = (size_t)b * kN * kM;
  const size_t brow = (size_t)b * kN;
  const int row0 = chunk * 256 + wv * 4 + sub;
  const float* rp = bank + bbase + (size_t)row0 * kM + m8;
  float4 c0 = *(const float4*)rp;
  float4 c1 = *(const float4*)(rp + 4);
  float w0p = wwv[brow + row0];
  float w1p = wwv[kWN + brow + row0];
  float wr0p = wrv[brow + row0];
  for (int it = 0; it < 16; it++) {
    float v[8] = {c0.x, c0.y, c0.z, c0.w, c1.x, c1.y, c1.z, c1.w};
    const float w0 = w0p, w1 = w1p, wr0 = wr0p;
    if (it < 15) {
      const int nrow = row0 + (it + 1) * 16;
      const float* np = bank + bbase + (size_t)nrow * kM + m8;
      c0 = *(const float4*)np;
      c1 = *(const float4*)(np + 4);
      w0p = wwv[brow + nrow];
      w1p = wwv[kWN + brow + nrow];
      wr0p = wrv[brow + nrow];
    }
    const int row = row0 + it * 16;
#pragma unroll
    for (int t = 0; t < 8; t++) {
      v[t] += w0 * (a0r[t] - e0r[t] * v[t]);        // -> B1
      racc[t] += wr0 * v[t];                         // read0 from B1
      v[t] += w1 * (a1r[t] - e1r[t] * v[t]);        // -> B2
    }
    float s[9] = {};
#pragma unroll
    for (int t = 0; t < 8; t++) {
      float ve = v[t] * e2r[t];
      s[0] += v[t] * kr1r[t];
      s[1] += v[t] * kw2r[t];
      s[2] += v[t] * v[t];
      s[3] += v[t] * kr2r[t];
      s[4] += ve * kr2r[t];
      s[5] += ve * v[t];
      s[6] += ve * ve;
      s[7] += v[t] * a2r[t];
      s[8] += ve * a2r[t];
    }
#pragma unroll
    for (int m = 1; m < 16; m <<= 1)
#pragma unroll
      for (int k = 0; k < 9; k++) s[k] += __shfl_xor(s[k], m, 64);
    if (lm == 0) {
#pragma unroll
      for (int k = 0; k < 9; k++) mB[(size_t)k * kWN + brow + row] = s[k];
    }
  }
  __syncthreads();
#pragma unroll
  for (int t = 0; t < 8; t++) {
    racc[t] += __shfl_xor(racc[t], 16, 64);
    racc[t] += __shfl_xor(racc[t], 32, 64);
  }
  if (sub == 0) {
#pragma unroll
    for (int t = 0; t < 8; t++) atomicAdd(&rlds[m8 + t], racc[t]);
  }
  __syncthreads();
  if (tid < kM) atomicAdd(&cat[(size_t)b * kCatW + tid], rlds[tid]);
}

// =============== A34: wr1, w2, wr2 from pass-B moments (1024 thr) ===============
__global__ __launch_bounds__(1024) void a34_k(const float* __restrict__ mB,
                                              const float* __restrict__ scal,
                                              const float* __restrict__ sdot,
                                              const float* __restrict__ read_w_prev,
                                              const float* __restrict__ write_w_prev,
                                              float* __restrict__ wwv,
                                              float* __restrict__ wrv) {
  const int b = blockIdx.x;
  const int tid = threadIdx.x;
  __shared__ float wb[kN];
  __shared__ float red[16];
  const size_t brow = (size_t)b * kN;
  float loc[4], w2r[4];
  // phase 1: read head 1 on B2 (direct)
  {
    const float* sc = scal + ((size_t)4 * kB + b) * 8;
    const float beta = sc[0], kn = sc[6];
#pragma unroll
    for (int i = 0; i < 4; i++) {
      size_t idx = brow + tid + i * 1024;
      float d = mB[0 * (size_t)kWN + idx];
      float q = mB[2 * (size_t)kWN + idx];
      loc[i] = beta * d / fmaxf(sqrtf(fmaxf(q, 0.f)) * kn, 1e-8f);
    }
    addr_core4(tid, loc, sc, read_w_prev + kWN + brow, wb, red);
#pragma unroll
    for (int i = 0; i < 4; i++) wrv[kWN + brow + tid + i * 1024] = loc[i];
  }
  // phase 2: write head 2 on B2 (direct)
  {
    const float* sc = scal + ((size_t)2 * kB + b) * 8;
    const float beta = sc[0], kn = sc[6];
#pragma unroll
    for (int i = 0; i < 4; i++) {
      size_t idx = brow + tid + i * 1024;
      float d = mB[1 * (size_t)kWN + idx];
      float q = mB[2 * (size_t)kWN + idx];
      loc[i] = beta * d / fmaxf(sqrtf(fmaxf(q, 0.f)) * kn, 1e-8f);
    }
    addr_core4(tid, loc, sc, write_w_prev + 2 * kWN + brow, wb, red);
#pragma unroll
    for (int i = 0; i < 4; i++) { wwv[2 * (size_t)kWN + brow + tid + i * 1024] = loc[i]; w2r[i] = loc[i]; }
  }
  // phase 3: read head 2 on B3 (expanded)
  {
    const float* sc = scal + ((size_t)5 * kB + b) * 8;
    const float beta = sc[0], kn = sc[6];
    const float sa2kr2 = sdot[b * 8 + 3], sa2a2 = sdot[b * 8 + 4];
#pragma unroll
    for (int i = 0; i < 4; i++) {
      size_t idx = brow + tid + i * 1024;
      float w2 = w2r[i], w2q = w2 * w2;
      float q3 = mB[2 * (size_t)kWN + idx]
               - 2.f * w2 * mB[5 * (size_t)kWN + idx]
               + w2q * mB[6 * (size_t)kWN + idx]
               + 2.f * w2 * mB[7 * (size_t)kWN + idx]
               - 2.f * w2q * mB[8 * (size_t)kWN + idx]
               + w2q * sa2a2;
      float d = mB[3 * (size_t)kWN + idx] - w2 * mB[4 * (size_t)kWN + idx] + w2 * sa2kr2;
      loc[i] = beta * d / fmaxf(sqrtf(fmaxf(q3, 0.f)) * kn, 1e-8f);
    }
    addr_core4(tid, loc, sc, read_w_prev + 2 * kWN + brow, wb, red);
#pragma unroll
    for (int i = 0; i < 4; i++) wrv[2 * (size_t)kWN + brow + tid + i * 1024] = loc[i];
  }
}

// =============== Pass C: chain(w0,w1,w2), read1 from B2, read2 from B3 ===============
__global__ __launch_bounds__(256, 4) void passC_k(const float* __restrict__ bank,
                                                  const float* __restrict__ wwv,
                                                  const float* __restrict__ wrv,
                                                  const float* __restrict__ evb,
                                                  const float* __restrict__ avb,
                                                  float* __restrict__ cat) {
  const int b = blockIdx.y, chunk = blockIdx.x;
  const int tid = threadIdx.x;
  const int lane = tid & 63, wv = tid >> 6, sub = lane >> 4, lm = lane & 15;
  const int m8 = lm * 8;
  float e_r[3][8], a_r[3][8];
#pragma unroll
  for (int j = 0; j < 3; j++)
#pragma unroll
    for (int t = 0; t < 8; t++) {
      e_r[j][t] = evb[((size_t)j * kB + b) * kM + m8 + t];
      a_r[j][t] = avb[((size_t)j * kB + b) * kM + m8 + t];
    }
  float racc1[8] = {}, racc2[8] = {};
  __shared__ float rlds[2][kM];
  if (tid < kM) { rlds[0][tid] = 0.f; rlds[1][tid] = 0.f; }
  const size_t bbase = (size_t)b * kN * kM;
  const size_t brow = (size_t)b * kN;
  const int row0 = chunk * 256 + wv * 4 + sub;
  const float* rp = bank + bbase + (size_t)row0 * kM + m8;
  float4 c0 = *(const float4*)rp;
  float4 c1 = *(const float4*)(rp + 4);
  float w0p = wwv[brow + row0];
  float w1p = wwv[kWN + brow + row0];
  float w2p = wwv[2 * (size_t)kWN + brow + row0];
  float wr1p = wrv[kWN + brow + row0];
  float wr2p = wrv[2 * (size_t)kWN + brow + row0];
  for (int it = 0; it < 16; it++) {
    float v[8] = {c0.x, c0.y, c0.z, c0.w, c1.x, c1.y, c1.z, c1.w};
    const float w0 = w0p, w1 = w1p, w2 = w2p, wr1 = wr1p, wr2 = wr2p;
    if (it < 15) {
      const int nrow = row0 + (it + 1) * 16;
      const float* np = bank + bbase + (size_t)nrow * kM + m8;
      c0 = *(const float4*)np;
      c1 = *(const float4*)(np + 4);
      w0p = wwv[brow + nrow];
      w1p = wwv[kWN + brow + nrow];
      w2p = wwv[2 * (size_t)kWN + brow + nrow];
      wr1p = wrv[kWN + brow + nrow];
      wr2p = wrv[2 * (size_t)kWN + brow + nrow];
    }
#pragma unroll
    for (int t = 0; t < 8; t++) {
      v[t] += w0 * (a_r[0][t] - e_r[0][t] * v[t]);  // B1
      v[t] += w1 * (a_r[1][t] - e_r[1][t] * v[t]);  // B2
      racc1[t] += wr1 * v[t];
      v[t] += w2 * (a_r[2][t] - e_r[2][t] * v[t]);  // B3
      racc2[t] += wr2 * v[t];
    }
  }
  __syncthreads();
#pragma unroll
  for (int t = 0; t < 8; t++) {
    racc1[t] += __shfl_xor(racc1[t], 16, 64);
    racc1[t] += __shfl_xor(racc1[t], 32, 64);
    racc2[t] += __shfl_xor(racc2[t], 16, 64);
    racc2[t] += __shfl_xor(racc2[t], 32, 64);
  }
  if (sub == 0) {
#pragma unroll
    for (int t = 0; t < 8; t++) {
      atomicAdd(&rlds[0][m8 + t], racc1[t]);
      atomicAdd(&rlds[1][m8 + t], racc2[t]);
    }
  }
  __syncthreads();
  if (tid < kM) {
    atomicAdd(&cat[(size_t)b * kCatW + kM + tid], rlds[0][tid]);
    atomicAdd(&cat[(size_t)b * kCatW + 2 * kM + tid], rlds[1][tid]);
  }
}

// =============== out GEMM: split-K atomic (out pre-initialized with bias) ===============
__global__ __launch_bounds__(256) void out_gemm(const float* __restrict__ A,
                                                const float* __restrict__ W,
                                                float* __restrict__ C) {
  __shared__ float As[64][68];
  __shared__ float Ws[64][68];
  const int tid = threadIdx.x;
  const int j0 = blockIdx.x * 64;
  const int b0 = (tid & 15) * 4;
  const int j4 = (tid >> 4) * 4;
  float acc[4][4] = {};
  for (int kc = 0; kc < 2; kc++) {
    const int k0 = blockIdx.y * 128 + kc * 64;
    __syncthreads();
#pragma unroll
    for (int i = 0; i < 4; i++) {
      int idx = tid + i * 256;
      int bb = idx >> 4;
      int kk = (idx & 15) * 4;
      float4 v = *(const float4*)(A + (size_t)bb * kCatW + k0 + kk);
      As[kk][bb] = v.x; As[kk + 1][bb] = v.y; As[kk + 2][bb] = v.z; As[kk + 3][bb] = v.w;
      float4 w = *(const float4*)(W + (size_t)(j0 + bb) * kCatW + k0 + kk);
      Ws[kk][bb] = w.x; Ws[kk + 1][bb] = w.y; Ws[kk + 2][bb] = w.z; Ws[kk + 3][bb] = w.w;
    }
    __syncthreads();
#pragma unroll 2
    for (int k = 0; k < 64; k++) {
      float4 av = *(const float4*)&As[k][b0];
      float4 wv = *(const float4*)&Ws[k][j4];
      float aa[4] = {av.x, av.y, av.z, av.w};
      float ww[4] = {wv.x, wv.y, wv.z, wv.w};
#pragma unroll
      for (int ii = 0; ii < 4; ii++)
#pragma unroll
        for (int jj = 0; jj < 4; jj++) acc[ii][jj] += aa[ii] * ww[jj];
    }
  }
#pragma unroll
  for (int ii = 0; ii < 4; ii++)
#pragma unroll
    for (int jj = 0; jj < 4; jj++)
      atomicAdd(&C[(size_t)(b0 + ii) * kO + j0 + j4 + jj], acc[ii][jj]);
}

}  // namespace

extern "C" void kernel_launch(void* const* d_in, const int* in_sizes, int n_in,
                              void* d_out, int out_size, void* d_ws, size_t ws_size,
                              hipStream_t stream) {
  const float* x            = (const float*)d_in[0];
  const float* h_prev       = (const float*)d_in[1];
  const float* c_prev       = (const float*)d_in[2];
  const float* bank         = (const float*)d_in[3];
  const float* read_w_prev  = (const float*)d_in[4];
  const float* write_w_prev = (const float*)d_in[5];
  const float* W_ih         = (const float*)d_in[6];
  const float* W_hh         = (const float*)d_in[7];
  const float* b_ih         = (const float*)d_in[8];
  const float* b_hh         = (const float*)d_in[9];
  const float* read_W       = (const float*)d_in[10];
  const float* read_b       = (const float*)d_in[11];
  const float* write_W      = (const float*)d_in[12];
  const float* write_b      = (const float*)d_in[13];
  const float* out_W        = (const float*)d_in[14];
  const float* out_b        = (const float*)d_in[15];
  float* out = (float*)d_out;

  float* ws    = (float*)d_ws;
  float* gates = ws;                         // 64*2048
  float* praw  = gates + kB * kGates;        // 64*1600
  float* cat   = praw + kB * kPRow;          // 64*896
  float* kwb   = cat + kB * kCatW;           // 3*64*128
  float* krb   = kwb + 3 * kB * kM;
  float* evb   = krb + 3 * kB * kM;
  float* avb   = evb + 3 * kB * kM;
  float* scal  = avb + 3 * kB * kM;          // 6*64*8
  float* sdot  = scal + 6 * kB * 8;          // 64*8
  float* wwv   = sdot + kB * 8;              // 3 planes (B,N)
  float* wrv   = wwv + 3 * kWN;              // 3 planes
  float* mA    = wrv + 3 * kWN;              // 10 planes
  float* mB    = mA + 10 * (size_t)kWN;      // 9 planes

  gates_gemm<<<33, 256, 0, stream>>>(x, W_ih, h_prev, W_hh, gates, out_b, out, cat);
  lstm_nl<<<(kB * kH) / 256, 256, 0, stream>>>(gates, b_ih, b_hh, c_prev, cat);
  proj_gemm<<<25, 256, 0, stream>>>(cat, write_W, read_W, praw);
  split_params<<<64, 128, 0, stream>>>(praw, write_b, read_b, kwb, krb, evb, avb, scal, sdot);

  passA_k<<<dim3(16, kB), 256, 0, stream>>>(bank, kwb, krb, evb, avb, mA);
  a12_k<<<64, 1024, 0, stream>>>(mA, scal, sdot, read_w_prev, write_w_prev, wwv, wrv);
  passB_k<<<dim3(16, kB), 256, 0, stream>>>(bank, wwv, wrv, kwb, krb, evb, avb, cat, mB);
  a34_k<<<64, 1024, 0, stream>>>(mB, scal, sdot, read_w_prev, write_w_prev, wwv, wrv);
  passC_k<<<dim3(16, kB), 256, 0, stream>>>(bank, wwv, wrv, evb, avb, cat);
  out_gemm<<<dim3(kO / 64, kCatW / 128), 256, 0, stream>>>(cat, out_W, out);

  (void)in_sizes; (void)n_in; (void)out_size; (void)ws_size;
}

// Round 6
// 436.017 us; speedup vs baseline: 1.8342x; 1.0211x over previous
//
#include <hip/hip_runtime.h>
#include <math.h>

namespace {

constexpr int kB = 64;
constexpr int kN = 4096;
constexpr int kM = 128;
constexpr int kH = 512;
constexpr int kE = 256;
constexpr int kO = 256;
constexpr int kGates = 4 * kH;       // 2048
constexpr int kCatW = 3 * kM + kH;   // 896  (read0|read1|read2|h)
constexpr int kPRow = 1600;          // padded 1572
constexpr int kWN = kB * kN;
constexpr float kLog2e = 1.4426950408889634f;

__device__ __forceinline__ float sigm_(float x) { return 1.f / (1.f + expf(-x)); }
__device__ __forceinline__ float softplus_(float x) { return x > 20.f ? x : log1pf(expf(x)); }

// =============== K1: gates GEMM (128 compute blocks + 1 init block) ===============
// block: b-slice of 16 (bs=bid>>5) x j-tile of 64 (jt=bid&31). No atomics.
__global__ __launch_bounds__(256) void gates_gemm(const float* __restrict__ x,
                                                  const float* __restrict__ W_ih,
                                                  const float* __restrict__ h_prev,
                                                  const float* __restrict__ W_hh,
                                                  float* __restrict__ gates,
                                                  const float* __restrict__ out_b,
                                                  float* __restrict__ out,
                                                  float* __restrict__ cat) {
  if (blockIdx.x == 128) {   // init block
    const int tid = threadIdx.x;
    for (int i = tid; i < kB * kO; i += 256) out[i] = out_b[i & (kO - 1)];
    for (int i = tid; i < kB * 384; i += 256) cat[(i / 384) * kCatW + (i % 384)] = 0.f;
    return;
  }
  __shared__ float At[64 * 20];    // [k][b] pad 20
  __shared__ float Wt[64 * 65];    // [k][j] pad 65
  const int tid = threadIdx.x;
  const int b0 = (blockIdx.x >> 5) * 16;
  const int j0 = (blockIdx.x & 31) * 64;
  const int jg = tid & 63;
  const int bq4 = (tid >> 6) * 4;
  float acc[4] = {};
  for (int kc = 0; kc < 12; kc++) {
    const bool isx = kc < 4;
    const float* A = isx ? x : h_prev;
    const float* W = isx ? W_ih : W_hh;
    const int lda = isx ? kE : kH;
    const int k0 = (isx ? kc : (kc - 4)) * 64;
    __syncthreads();
    {  // A tile: 16 b x 64 k
      int bb = tid >> 4;
      int kk = (tid & 15) * 4;
      float4 v = *(const float4*)(A + (size_t)(b0 + bb) * lda + k0 + kk);
      At[(kk + 0) * 20 + bb] = v.x; At[(kk + 1) * 20 + bb] = v.y;
      At[(kk + 2) * 20 + bb] = v.z; At[(kk + 3) * 20 + bb] = v.w;
    }
#pragma unroll
    for (int i = 0; i < 4; i++) {  // W tile: 64 j x 64 k
      int idx = tid + i * 256;
      int jj = idx >> 4;
      int kk = (idx & 15) * 4;
      float4 w = *(const float4*)(W + (size_t)(j0 + jj) * lda + k0 + kk);
      Wt[(kk + 0) * 65 + jj] = w.x; Wt[(kk + 1) * 65 + jj] = w.y;
      Wt[(kk + 2) * 65 + jj] = w.z; Wt[(kk + 3) * 65 + jj] = w.w;
    }
    __syncthreads();
#pragma unroll 4
    for (int k = 0; k < 64; k++) {
      float4 av = *(const float4*)&At[k * 20 + bq4];
      float wv = Wt[k * 65 + jg];
      acc[0] += av.x * wv; acc[1] += av.y * wv; acc[2] += av.z * wv; acc[3] += av.w * wv;
    }
  }
#pragma unroll
  for (int i = 0; i < 4; i++)
    gates[(size_t)(b0 + bq4 + i) * kGates + j0 + jg] = acc[i];
}

// =============== K2: head projections GEMM with fused LSTM h-compute ===============
// 200 blocks: bs = bid/25 (b-slice of 8), jt = bid%25 (j-tile of 64)
__global__ __launch_bounds__(256) void proj_gemm(const float* __restrict__ gates,
                                                 const float* __restrict__ b_ih,
                                                 const float* __restrict__ b_hh,
                                                 const float* __restrict__ c_prev,
                                                 const float* __restrict__ write_W,
                                                 const float* __restrict__ read_W,
                                                 float* __restrict__ praw,
                                                 float* __restrict__ cat) {
  __shared__ float hs[512 * 12];   // [k][b] pad 12 (b-slice of 8)
  __shared__ float Wt[64 * 65];    // [k][j]
  const int tid = threadIdx.x;
  const int bs = blockIdx.x / 25;
  const int jt = blockIdx.x % 25;
  const int b0 = bs * 8;
  const int j0 = jt * 64;
  // compute h slice from gates
  for (int i = tid; i < 8 * 512; i += 256) {
    int bb = i >> 9, kk = i & 511;
    int b = b0 + bb;
    const float* g = gates + (size_t)b * kGates;
    float i_ = g[kk]           + b_ih[kk]           + b_hh[kk];
    float f_ = g[512 + kk]     + b_ih[512 + kk]     + b_hh[512 + kk];
    float g_ = g[1024 + kk]    + b_ih[1024 + kk]    + b_hh[1024 + kk];
    float o_ = g[1536 + kk]    + b_ih[1536 + kk]    + b_hh[1536 + kk];
    float c = sigm_(f_) * c_prev[(size_t)b * kH + kk] + sigm_(i_) * tanhf(g_);
    float h = sigm_(o_) * tanhf(c);
    hs[kk * 12 + bb] = h;
    if (jt == 0) cat[(size_t)b * kCatW + 3 * kM + kk] = h;
  }
  const int jg = tid & 63;
  const int bq2 = (tid >> 6) * 2;
  float acc[2] = {};
  for (int kc = 0; kc < 8; kc++) {
    const int k0 = kc * 64;
    __syncthreads();
#pragma unroll
    for (int i = 0; i < 4; i++) {
      int idx = tid + i * 256;
      int jj = idx >> 4;
      int kk = (idx & 15) * 4;
      int j = j0 + jj;
      float4 w = make_float4(0.f, 0.f, 0.f, 0.f);
      if (j < 1170)      w = *(const float4*)(write_W + (size_t)j * kH + k0 + kk);
      else if (j < 1572) w = *(const float4*)(read_W + (size_t)(j - 1170) * kH + k0 + kk);
      Wt[(kk + 0) * 65 + jj] = w.x; Wt[(kk + 1) * 65 + jj] = w.y;
      Wt[(kk + 2) * 65 + jj] = w.z; Wt[(kk + 3) * 65 + jj] = w.w;
    }
    __syncthreads();
#pragma unroll 4
    for (int k = 0; k < 64; k++) {
      float2 av = *(const float2*)&hs[(k0 + k) * 12 + bq2];
      float wv = Wt[k * 65 + jg];
      acc[0] += av.x * wv; acc[1] += av.y * wv;
    }
  }
  if (j0 + jg < 1572) {
    praw[(size_t)(b0 + bq2 + 0) * kPRow + j0 + jg] = acc[0];
    praw[(size_t)(b0 + bq2 + 1) * kPRow + j0 + jg] = acc[1];
  }
}

// =============== split head params + per-batch scalar dots ===============
__global__ __launch_bounds__(128) void split_params(const float* __restrict__ praw,
                                                    const float* __restrict__ write_b,
                                                    const float* __restrict__ read_b,
                                                    float* __restrict__ kwb, float* __restrict__ krb,
                                                    float* __restrict__ evb, float* __restrict__ avb,
                                                    float* __restrict__ scal,
                                                    float* __restrict__ sdot) {
  const int b = blockIdx.x;
  const int m = threadIdx.x;
  __shared__ float red[2];
  for (int i = 0; i < 3; i++) {  // write heads
    const float* p = praw + (size_t)b * kPRow + i * 390;
    const float* wb = write_b + i * 390;
    float kv = p[m] + wb[m];
    kwb[((size_t)i * kB + b) * kM + m] = kv;
    evb[((size_t)i * kB + b) * kM + m] = sigm_(p[134 + m] + wb[134 + m]);
    avb[((size_t)i * kB + b) * kM + m] = p[262 + m] + wb[262 + m];
    float sq = kv * kv;
#pragma unroll
    for (int mm = 1; mm < 64; mm <<= 1) sq += __shfl_xor(sq, mm, 64);
    __syncthreads();
    if ((m & 63) == 0) red[m >> 6] = sq;
    __syncthreads();
    if (m == 0) {
      float* s = scal + ((size_t)i * kB + b) * 8;
      s[0] = softplus_(p[128] + wb[128]);
      s[1] = sigm_(p[129] + wb[129]);
      s[2] = 1.f + softplus_(p[133] + wb[133]);
      float x0 = p[130] + wb[130], x1 = p[131] + wb[131], x2 = p[132] + wb[132];
      float mx = fmaxf(x0, fmaxf(x1, x2));
      float e0 = expf(x0 - mx), e1 = expf(x1 - mx), e2 = expf(x2 - mx);
      float si = 1.f / (e0 + e1 + e2);
      s[3] = e0 * si; s[4] = e1 * si; s[5] = e2 * si;
      s[6] = sqrtf(red[0] + red[1]);
    }
    __syncthreads();
  }
  for (int i = 0; i < 3; i++) {  // read heads
    const float* p = praw + (size_t)b * kPRow + 1170 + i * 134;
    const float* rb = read_b + i * 134;
    float kv = p[m] + rb[m];
    krb[((size_t)i * kB + b) * kM + m] = kv;
    float sq = kv * kv;
#pragma unroll
    for (int mm = 1; mm < 64; mm <<= 1) sq += __shfl_xor(sq, mm, 64);
    __syncthreads();
    if ((m & 63) == 0) red[m >> 6] = sq;
    __syncthreads();
    if (m == 0) {
      float* s = scal + ((size_t)(3 + i) * kB + b) * 8;
      s[0] = softplus_(p[128] + rb[128]);
      s[1] = sigm_(p[129] + rb[129]);
      s[2] = 1.f + softplus_(p[133] + rb[133]);
      float x0 = p[130] + rb[130], x1 = p[131] + rb[131], x2 = p[132] + rb[132];
      float mx = fmaxf(x0, fmaxf(x1, x2));
      float e0 = expf(x0 - mx), e1 = expf(x1 - mx), e2 = expf(x2 - mx);
      float si = 1.f / (e0 + e1 + e2);
      s[3] = e0 * si; s[4] = e1 * si; s[5] = e2 * si;
      s[6] = sqrtf(red[0] + red[1]);
    }
    __syncthreads();
  }
  // per-batch scalar dots: {a0.kr0, a0.kw1, a0.a0, a2.kr2, a2.a2}
  __syncthreads();
  if (m < 64) {
    const float* a0 = avb + ((size_t)0 * kB + b) * kM;
    const float* a2 = avb + ((size_t)2 * kB + b) * kM;
    const float* u[5] = {a0, a0, a0, a2, a2};
    const float* v[5] = {krb + ((size_t)0 * kB + b) * kM,
                         kwb + ((size_t)1 * kB + b) * kM,
                         a0,
                         krb + ((size_t)2 * kB + b) * kM,
                         a2};
#pragma unroll
    for (int d = 0; d < 5; d++) {
      float s = u[d][m] * v[d][m] + u[d][m + 64] * v[d][m + 64];
#pragma unroll
      for (int mm = 1; mm < 64; mm <<= 1) s += __shfl_xor(s, mm, 64);
      if (m == 0) sdot[b * 8 + d] = s;
    }
  }
}

// =============== Pass A: B0 moments (depth-2 pipeline, packed mA[n][12]) ===============
// slots: 0:B.kw0 1:B.B 2:B.kr0 3:B.(e0kr0) 4:B.kw1 5:B.(e0kw1)
//        6:SumB2e0 7:SumB2e0^2 8:B.a0 9:B.(e0a0)  (10,11 pad)
__global__ __launch_bounds__(256) void passA_k(const float* __restrict__ bank,
                                               const float* __restrict__ kwb,
                                               const float* __restrict__ krb,
                                               const float* __restrict__ evb,
                                               const float* __restrict__ avb,
                                               float* __restrict__ mA) {
  const int b = blockIdx.y, chunk = blockIdx.x;
  const int tid = threadIdx.x;
  const int lane = tid & 63, wv = tid >> 6, sub = lane >> 4, lm = lane & 15;
  const int m8 = lm * 8;
  float kw0r[8], kr0r[8], kw1r[8], a0r[8], e0r[8];
#pragma unroll
  for (int t = 0; t < 8; t++) {
    kw0r[t] = kwb[((size_t)0 * kB + b) * kM + m8 + t];
    kr0r[t] = krb[((size_t)0 * kB + b) * kM + m8 + t];
    kw1r[t] = kwb[((size_t)1 * kB + b) * kM + m8 + t];
    a0r[t]  = avb[((size_t)0 * kB + b) * kM + m8 + t];
    e0r[t]  = evb[((size_t)0 * kB + b) * kM + m8 + t];
  }
  const size_t bbase = (size_t)b * kN * kM;
  const size_t brow = (size_t)b * kN;
  const int row0 = chunk * 256 + wv * 4 + sub;
  const float* base = bank + bbase + (size_t)row0 * kM + m8;
  float4 pA0 = *(const float4*)(base);
  float4 pA1 = *(const float4*)(base + 4);
  float4 pB0 = *(const float4*)(base + (size_t)16 * kM);
  float4 pB1 = *(const float4*)(base + (size_t)16 * kM + 4);
  for (int it = 0; it < 16; it++) {
    float v[8];
    if ((it & 1) == 0) {
      v[0]=pA0.x; v[1]=pA0.y; v[2]=pA0.z; v[3]=pA0.w; v[4]=pA1.x; v[5]=pA1.y; v[6]=pA1.z; v[7]=pA1.w;
      if (it + 2 < 16) {
        const float* np = base + (size_t)(it + 2) * 16 * kM;
        pA0 = *(const float4*)np; pA1 = *(const float4*)(np + 4);
      }
    } else {
      v[0]=pB0.x; v[1]=pB0.y; v[2]=pB0.z; v[3]=pB0.w; v[4]=pB1.x; v[5]=pB1.y; v[6]=pB1.z; v[7]=pB1.w;
      if (it + 2 < 16) {
        const float* np = base + (size_t)(it + 2) * 16 * kM;
        pB0 = *(const float4*)np; pB1 = *(const float4*)(np + 4);
      }
    }
    const int row = row0 + it * 16;
    float s[10] = {};
#pragma unroll
    for (int t = 0; t < 8; t++) {
      float be = v[t] * e0r[t];
      s[0] += v[t] * kw0r[t];
      s[1] += v[t] * v[t];
      s[2] += v[t] * kr0r[t];
      s[3] += be * kr0r[t];
      s[4] += v[t] * kw1r[t];
      s[5] += be * kw1r[t];
      s[6] += be * v[t];
      s[7] += be * be;
      s[8] += v[t] * a0r[t];
      s[9] += be * a0r[t];
    }
#pragma unroll
    for (int m = 1; m < 16; m <<= 1)
#pragma unroll
      for (int k = 0; k < 10; k++) s[k] += __shfl_xor(s[k], m, 64);
    if (lm == 0) {
      float4* dst = (float4*)(mA + (size_t)(brow + row) * 12);
      dst[0] = make_float4(s[0], s[1], s[2], s[3]);
      dst[1] = make_float4(s[4], s[5], s[6], s[7]);
      dst[2] = make_float4(s[8], s[9], 0.f, 0.f);
    }
  }
}

// ===== addressing core (1024 threads, 4 elems/thread) =====
__device__ void addr_core4(int tid, float* loc, const float* sc, const float* __restrict__ wp,
                           float* wb, float* red) {
  const float g = sc[1], r = sc[2];
  const float s0 = sc[3], s1c = sc[4], s2 = sc[5];
  const int lane = tid & 63, wid = tid >> 6;  // wid 0..15
  __syncthreads();
  float mx = fmaxf(fmaxf(loc[0], loc[1]), fmaxf(loc[2], loc[3]));
#pragma unroll
  for (int m = 1; m < 64; m <<= 1) mx = fmaxf(mx, __shfl_xor(mx, m, 64));
  if (lane == 0) red[wid] = mx;
  __syncthreads();
  mx = red[0];
#pragma unroll
  for (int k = 1; k < 16; k++) mx = fmaxf(mx, red[k]);
  float sum = 0.f;
#pragma unroll
  for (int i = 0; i < 4; i++) { loc[i] = exp2f((loc[i] - mx) * kLog2e); sum += loc[i]; }
#pragma unroll
  for (int m = 1; m < 64; m <<= 1) sum += __shfl_xor(sum, m, 64);
  __syncthreads();
  if (lane == 0) red[wid] = sum;
  __syncthreads();
  sum = red[0];
#pragma unroll
  for (int k = 1; k < 16; k++) sum += red[k];
  const float inv = 1.f / sum;
  const float omg = 1.f - g;
#pragma unroll
  for (int i = 0; i < 4; i++) {
    int n = tid + i * 1024;
    wb[n] = loc[i] * inv + omg * wp[n];
  }
  __syncthreads();
  float ssum = 0.f;
#pragma unroll
  for (int i = 0; i < 4; i++) {
    int n = tid + i * 1024;
    float sh = s0 * wb[(n + kN - 1) & (kN - 1)] + s1c * wb[n] + s2 * wb[(n + 1) & (kN - 1)];
    float y = (sh > 0.f) ? exp2f(r * log2f(sh)) : 0.f;
    loc[i] = y;
    ssum += y;
  }
#pragma unroll
  for (int m = 1; m < 64; m <<= 1) ssum += __shfl_xor(ssum, m, 64);
  __syncthreads();
  if (lane == 0) red[wid] = ssum;
  __syncthreads();
  ssum = red[0];
#pragma unroll
  for (int k = 1; k < 16; k++) ssum += red[k];
  const float invs = 1.f / (ssum + 1e-8f);
#pragma unroll
  for (int i = 0; i < 4; i++) loc[i] *= invs;
  __syncthreads();
}

// =============== A12: w0, wr0, w1 -> wpack slots {0,2,1} ===============
__global__ __launch_bounds__(1024) void a12_k(const float* __restrict__ mA,
                                              const float* __restrict__ scal,
                                              const float* __restrict__ sdot,
                                              const float* __restrict__ read_w_prev,
                                              const float* __restrict__ write_w_prev,
                                              float* __restrict__ wpack) {
  const int b = blockIdx.x;
  const int tid = threadIdx.x;
  __shared__ float wb[kN];
  __shared__ float red[16];
  const size_t brow = (size_t)b * kN;
  float loc[4], w0r[4], q1r[4];
  // phase 1: write head 0 on B0
  {
    const float* sc = scal + ((size_t)0 * kB + b) * 8;
    const float beta = sc[0], kn = sc[6];
#pragma unroll
    for (int i = 0; i < 4; i++) {
      const float* mp = mA + (size_t)(brow + tid + i * 1024) * 12;
      float4 q0 = *(const float4*)mp;
      loc[i] = beta * q0.x / fmaxf(sqrtf(fmaxf(q0.y, 0.f)) * kn, 1e-8f);
    }
    addr_core4(tid, loc, sc, write_w_prev + brow, wb, red);
#pragma unroll
    for (int i = 0; i < 4; i++) {
      wpack[(size_t)(brow + tid + i * 1024) * 8 + 0] = loc[i];
      w0r[i] = loc[i];
    }
  }
  // phase 2: read head 0 on B1 (expanded)
  {
    const float* sc = scal + ((size_t)3 * kB + b) * 8;
    const float beta = sc[0], kn = sc[6];
    const float sa0kr0 = sdot[b * 8 + 0], sa0a0 = sdot[b * 8 + 2];
#pragma unroll
    for (int i = 0; i < 4; i++) {
      const float* mp = mA + (size_t)(brow + tid + i * 1024) * 12;
      float4 q0 = *(const float4*)mp;          // 0..3
      float4 q1 = *(const float4*)(mp + 4);    // 4..7
      float4 q2 = *(const float4*)(mp + 8);    // 8..11
      float w0 = w0r[i], w0q = w0 * w0;
      float q1v = q0.y
                - 2.f * w0 * q1.z
                + w0q * q1.w
                + 2.f * w0 * q2.x
                - 2.f * w0q * q2.y
                + w0q * sa0a0;
      q1r[i] = q1v;
      float d = q0.z - w0 * q0.w + w0 * sa0kr0;
      loc[i] = beta * d / fmaxf(sqrtf(fmaxf(q1v, 0.f)) * kn, 1e-8f);
    }
    addr_core4(tid, loc, sc, read_w_prev + brow, wb, red);
#pragma unroll
    for (int i = 0; i < 4; i++)
      wpack[(size_t)(brow + tid + i * 1024) * 8 + 2] = loc[i];
  }
  // phase 3: write head 1 on B1 (expanded)
  {
    const float* sc = scal + ((size_t)1 * kB + b) * 8;
    const float beta = sc[0], kn = sc[6];
    const float sa0kw1 = sdot[b * 8 + 1];
#pragma unroll
    for (int i = 0; i < 4; i++) {
      const float* mp = mA + (size_t)(brow + tid + i * 1024) * 12;
      float4 q1 = *(const float4*)(mp + 4);    // 4..7
      float w0 = w0r[i];
      float d = q1.x - w0 * q1.y + w0 * sa0kw1;
      loc[i] = beta * d / fmaxf(sqrtf(fmaxf(q1r[i], 0.f)) * kn, 1e-8f);
    }
    addr_core4(tid, loc, sc, write_w_prev + kWN + brow, wb, red);
#pragma unroll
    for (int i = 0; i < 4; i++)
      wpack[(size_t)(brow + tid + i * 1024) * 8 + 1] = loc[i];
  }
}

// =============== Pass B: chain(w0,w1), read0, B2 moments (packed mB[n][12]) ===============
// slots: 0:B2.kr1 1:B2.kw2 2:B2.B2 3:B2.kr2 4:B2.(e2kr2) 5:SumB2^2e2 6:SumB2^2e2^2 7:B2.a2 8:B2.(e2a2)
__global__ __launch_bounds__(256) void passB_k(const float* __restrict__ bank,
                                               const float* __restrict__ wpack,
                                               const float* __restrict__ kwb,
                                               const float* __restrict__ krb,
                                               const float* __restrict__ evb,
                                               const float* __restrict__ avb,
                                               float* __restrict__ cat,
                                               float* __restrict__ mB) {
  const int b = blockIdx.y, chunk = blockIdx.x;
  const int tid = threadIdx.x;
  const int lane = tid & 63, wv = tid >> 6, sub = lane >> 4, lm = lane & 15;
  const int m8 = lm * 8;
  float e0r[8], a0r[8], e1r[8], a1r[8], kr1r[8], kw2r[8], kr2r[8], e2r[8], a2r[8];
#pragma unroll
  for (int t = 0; t < 8; t++) {
    e0r[t]  = evb[((size_t)0 * kB + b) * kM + m8 + t];
    a0r[t]  = avb[((size_t)0 * kB + b) * kM + m8 + t];
    e1r[t]  = evb[((size_t)1 * kB + b) * kM + m8 + t];
    a1r[t]  = avb[((size_t)1 * kB + b) * kM + m8 + t];
    kr1r[t] = krb[((size_t)1 * kB + b) * kM + m8 + t];
    kw2r[t] = kwb[((size_t)2 * kB + b) * kM + m8 + t];
    kr2r[t] = krb[((size_t)2 * kB + b) * kM + m8 + t];
    e2r[t]  = evb[((size_t)2 * kB + b) * kM + m8 + t];
    a2r[t]  = avb[((size_t)2 * kB + b) * kM + m8 + t];
  }
  float racc[8] = {};
  __shared__ float rlds[kM];
  if (tid < kM) rlds[tid] = 0.f;
  const size_t bbase = (size_t)b * kN * kM;
  const size_t brow = (size_t)b * kN;
  const int row0 = chunk * 256 + wv * 4 + sub;
  const float* base = bank + bbase + (size_t)row0 * kM + m8;
  const float* wbase = wpack + (size_t)(brow + row0) * 8;
  float4 pA0 = *(const float4*)(base);
  float4 pA1 = *(const float4*)(base + 4);
  float4 wA  = *(const float4*)(wbase);
  float4 pB0 = *(const float4*)(base + (size_t)16 * kM);
  float4 pB1 = *(const float4*)(base + (size_t)16 * kM + 4);
  float4 wB  = *(const float4*)(wbase + (size_t)16 * 8);
  for (int it = 0; it < 16; it++) {
    float v[8];
    float w0, w1, wr0;
    if ((it & 1) == 0) {
      v[0]=pA0.x; v[1]=pA0.y; v[2]=pA0.z; v[3]=pA0.w; v[4]=pA1.x; v[5]=pA1.y; v[6]=pA1.z; v[7]=pA1.w;
      w0 = wA.x; w1 = wA.y; wr0 = wA.z;
      if (it + 2 < 16) {
        const float* np = base + (size_t)(it + 2) * 16 * kM;
        pA0 = *(const float4*)np; pA1 = *(const float4*)(np + 4);
        wA = *(const float4*)(wbase + (size_t)(it + 2) * 16 * 8);
      }
    } else {
      v[0]=pB0.x; v[1]=pB0.y; v[2]=pB0.z; v[3]=pB0.w; v[4]=pB1.x; v[5]=pB1.y; v[6]=pB1.z; v[7]=pB1.w;
      w0 = wB.x; w1 = wB.y; wr0 = wB.z;
      if (it + 2 < 16) {
        const float* np = base + (size_t)(it + 2) * 16 * kM;
        pB0 = *(const float4*)np; pB1 = *(const float4*)(np + 4);
        wB = *(const float4*)(wbase + (size_t)(it + 2) * 16 * 8);
      }
    }
    const int row = row0 + it * 16;
#pragma unroll
    for (int t = 0; t < 8; t++) {
      v[t] += w0 * (a0r[t] - e0r[t] * v[t]);        // -> B1
      racc[t] += wr0 * v[t];                         // read0 from B1
      v[t] += w1 * (a1r[t] - e1r[t] * v[t]);        // -> B2
    }
    float s[9] = {};
#pragma unroll
    for (int t = 0; t < 8; t++) {
      float ve = v[t] * e2r[t];
      s[0] += v[t] * kr1r[t];
      s[1] += v[t] * kw2r[t];
      s[2] += v[t] * v[t];
      s[3] += v[t] * kr2r[t];
      s[4] += ve * kr2r[t];
      s[5] += ve * v[t];
      s[6] += ve * ve;
      s[7] += v[t] * a2r[t];
      s[8] += ve * a2r[t];
    }
#pragma unroll
    for (int m = 1; m < 16; m <<= 1)
#pragma unroll
      for (int k = 0; k < 9; k++) s[k] += __shfl_xor(s[k], m, 64);
    if (lm == 0) {
      float4* dst = (float4*)(mB + (size_t)(brow + row) * 12);
      dst[0] = make_float4(s[0], s[1], s[2], s[3]);
      dst[1] = make_float4(s[4], s[5], s[6], s[7]);
      dst[2] = make_float4(s[8], 0.f, 0.f, 0.f);
    }
  }
  __syncthreads();
#pragma unroll
  for (int t = 0; t < 8; t++) {
    racc[t] += __shfl_xor(racc[t], 16, 64);
    racc[t] += __shfl_xor(racc[t], 32, 64);
  }
  if (sub == 0) {
#pragma unroll
    for (int t = 0; t < 8; t++) atomicAdd(&rlds[m8 + t], racc[t]);
  }
  __syncthreads();
  if (tid < kM) atomicAdd(&cat[(size_t)b * kCatW + tid], rlds[tid]);
}

// =============== A34: wr1, w2, wr2 -> wpack slots {4,3,5} ===============
__global__ __launch_bounds__(1024) void a34_k(const float* __restrict__ mB,
                                              const float* __restrict__ scal,
                                              const float* __restrict__ sdot,
                                              const float* __restrict__ read_w_prev,
                                              const float* __restrict__ write_w_prev,
                                              float* __restrict__ wpack) {
  const int b = blockIdx.x;
  const int tid = threadIdx.x;
  __shared__ float wb[kN];
  __shared__ float red[16];
  const size_t brow = (size_t)b * kN;
  float loc[4], w2r[4];
  // phase 1: read head 1 on B2 (direct)
  {
    const float* sc = scal + ((size_t)4 * kB + b) * 8;
    const float beta = sc[0], kn = sc[6];
#pragma unroll
    for (int i = 0; i < 4; i++) {
      const float* mp = mB + (size_t)(brow + tid + i * 1024) * 12;
      float4 q0 = *(const float4*)mp;
      loc[i] = beta * q0.x / fmaxf(sqrtf(fmaxf(q0.z, 0.f)) * kn, 1e-8f);
    }
    addr_core4(tid, loc, sc, read_w_prev + kWN + brow, wb, red);
#pragma unroll
    for (int i = 0; i < 4; i++)
      wpack[(size_t)(brow + tid + i * 1024) * 8 + 4] = loc[i];
  }
  // phase 2: write head 2 on B2 (direct)
  {
    const float* sc = scal + ((size_t)2 * kB + b) * 8;
    const float beta = sc[0], kn = sc[6];
#pragma unroll
    for (int i = 0; i < 4; i++) {
      const float* mp = mB + (size_t)(brow + tid + i * 1024) * 12;
      float4 q0 = *(const float4*)mp;
      loc[i] = beta * q0.y / fmaxf(sqrtf(fmaxf(q0.z, 0.f)) * kn, 1e-8f);
    }
    addr_core4(tid, loc, sc, write_w_prev + 2 * kWN + brow, wb, red);
#pragma unroll
    for (int i = 0; i < 4; i++) {
      wpack[(size_t)(brow + tid + i * 1024) * 8 + 3] = loc[i];
      w2r[i] = loc[i];
    }
  }
  // phase 3: read head 2 on B3 (expanded)
  {
    const float* sc = scal + ((size_t)5 * kB + b) * 8;
    const float beta = sc[0], kn = sc[6];
    const float sa2kr2 = sdot[b * 8 + 3], sa2a2 = sdot[b * 8 + 4];
#pragma unroll
    for (int i = 0; i < 4; i++) {
      const float* mp = mB + (size_t)(brow + tid + i * 1024) * 12;
      float4 q0 = *(const float4*)mp;          // 0..3
      float4 q1 = *(const float4*)(mp + 4);    // 4..7
      float4 q2 = *(const float4*)(mp + 8);    // 8..11
      float w2 = w2r[i], w2q = w2 * w2;
      float q3 = q0.z
               - 2.f * w2 * q1.y
               + w2q * q1.z
               + 2.f * w2 * q1.w
               - 2.f * w2q * q2.x
               + w2q * sa2a2;
      float d = q0.w - w2 * q1.x + w2 * sa2kr2;
      loc[i] = beta * d / fmaxf(sqrtf(fmaxf(q3, 0.f)) * kn, 1e-8f);
    }
    addr_core4(tid, loc, sc, read_w_prev + 2 * kWN + brow, wb, red);
#pragma unroll
    for (int i = 0; i < 4; i++)
      wpack[(size_t)(brow + tid + i * 1024) * 8 + 5] = loc[i];
  }
}

// =============== Pass C: chain(w0,w1,w2), read1 from B2, read2 from B3 ===============
__global__ __launch_bounds__(256) void passC_k(const float* __restrict__ bank,
                                               const float* __restrict__ wpack,
                                               const float* __restrict__ evb,
                                               const float* __restrict__ avb,
                                               float* __restrict__ cat) {
  const int b = blockIdx.y, chunk = blockIdx.x;
  const int tid = threadIdx.x;
  const int lane = tid & 63, wv = tid >> 6, sub = lane >> 4, lm = lane & 15;
  const int m8 = lm * 8;
  float e_r[3][8], a_r[3][8];
#pragma unroll
  for (int j = 0; j < 3; j++)
#pragma unroll
    for (int t = 0; t < 8; t++) {
      e_r[j][t] = evb[((size_t)j * kB + b) * kM + m8 + t];
      a_r[j][t] = avb[((size_t)j * kB + b) * kM + m8 + t];
    }
  float racc1[8] = {}, racc2[8] = {};
  __shared__ float rlds[2][kM];
  if (tid < kM) { rlds[0][tid] = 0.f; rlds[1][tid] = 0.f; }
  const size_t bbase = (size_t)b * kN * kM;
  const size_t brow = (size_t)b * kN;
  const int row0 = chunk * 256 + wv * 4 + sub;
  const float* base = bank + bbase + (size_t)row0 * kM + m8;
  const float* wbase = wpack + (size_t)(brow + row0) * 8;
  float4 pA0 = *(const float4*)(base);
  float4 pA1 = *(const float4*)(base + 4);
  float4 wAa = *(const float4*)(wbase);
  float4 wAb = *(const float4*)(wbase + 4);
  float4 pB0 = *(const float4*)(base + (size_t)16 * kM);
  float4 pB1 = *(const float4*)(base + (size_t)16 * kM + 4);
  float4 wBa = *(const float4*)(wbase + (size_t)16 * 8);
  float4 wBb = *(const float4*)(wbase + (size_t)16 * 8 + 4);
  for (int it = 0; it < 16; it++) {
    float v[8];
    float w0, w1, w2, wr1, wr2;
    if ((it & 1) == 0) {
      v[0]=pA0.x; v[1]=pA0.y; v[2]=pA0.z; v[3]=pA0.w; v[4]=pA1.x; v[5]=pA1.y; v[6]=pA1.z; v[7]=pA1.w;
      w0 = wAa.x; w1 = wAa.y; w2 = wAa.w; wr1 = wAb.x; wr2 = wAb.y;
      if (it + 2 < 16) {
        const float* np = base + (size_t)(it + 2) * 16 * kM;
        pA0 = *(const float4*)np; pA1 = *(const float4*)(np + 4);
        const float* wp = wbase + (size_t)(it + 2) * 16 * 8;
        wAa = *(const float4*)wp; wAb = *(const float4*)(wp + 4);
      }
    } else {
      v[0]=pB0.x; v[1]=pB0.y; v[2]=pB0.z; v[3]=pB0.w; v[4]=pB1.x; v[5]=pB1.y; v[6]=pB1.z; v[7]=pB1.w;
      w0 = wBa.x; w1 = wBa.y; w2 = wBa.w; wr1 = wBb.x; wr2 = wBb.y;
      if (it + 2 < 16) {
        const float* np = base + (size_t)(it + 2) * 16 * kM;
        pB0 = *(const float4*)np; pB1 = *(const float4*)(np + 4);
        const float* wp = wbase + (size_t)(it + 2) * 16 * 8;
        wBa = *(const float4*)wp; wBb = *(const float4*)(wp + 4);
      }
    }
#pragma unroll
    for (int t = 0; t < 8; t++) {
      v[t] += w0 * (a_r[0][t] - e_r[0][t] * v[t]);  // B1
      v[t] += w1 * (a_r[1][t] - e_r[1][t] * v[t]);  // B2
      racc1[t] += wr1 * v[t];
      v[t] += w2 * (a_r[2][t] - e_r[2][t] * v[t]);  // B3
      racc2[t] += wr2 * v[t];
    }
  }
  __syncthreads();
#pragma unroll
  for (int t = 0; t < 8; t++) {
    racc1[t] += __shfl_xor(racc1[t], 16, 64);
    racc1[t] += __shfl_xor(racc1[t], 32, 64);
    racc2[t] += __shfl_xor(racc2[t], 16, 64);
    racc2[t] += __shfl_xor(racc2[t], 32, 64);
  }
  if (sub == 0) {
#pragma unroll
    for (int t = 0; t < 8; t++) {
      atomicAdd(&rlds[0][m8 + t], racc1[t]);
      atomicAdd(&rlds[1][m8 + t], racc2[t]);
    }
  }
  __syncthreads();
  if (tid < kM) {
    atomicAdd(&cat[(size_t)b * kCatW + kM + tid], rlds[0][tid]);
    atomicAdd(&cat[(size_t)b * kCatW + 2 * kM + tid], rlds[1][tid]);
  }
}

// =============== out GEMM: split-K atomic (out pre-initialized with bias) ===============
__global__ __launch_bounds__(256) void out_gemm(const float* __restrict__ A,
                                                const float* __restrict__ W,
                                                float* __restrict__ C) {
  __shared__ float As[64][68];
  __shared__ float Ws[64][68];
  const int tid = threadIdx.x;
  const int j0 = blockIdx.x * 64;
  const int b0 = (tid & 15) * 4;
  const int j4 = (tid >> 4) * 4;
  float acc[4][4] = {};
  for (int kc = 0; kc < 2; kc++) {
    const int k0 = blockIdx.y * 128 + kc * 64;
    __syncthreads();
#pragma unroll
    for (int i = 0; i < 4; i++) {
      int idx = tid + i * 256;
      int bb = idx >> 4;
      int kk = (idx & 15) * 4;
      float4 v = *(const float4*)(A + (size_t)bb * kCatW + k0 + kk);
      As[kk][bb] = v.x; As[kk + 1][bb] = v.y; As[kk + 2][bb] = v.z; As[kk + 3][bb] = v.w;
      float4 w = *(const float4*)(W + (size_t)(j0 + bb) * kCatW + k0 + kk);
      Ws[kk][bb] = w.x; Ws[kk + 1][bb] = w.y; Ws[kk + 2][bb] = w.z; Ws[kk + 3][bb] = w.w;
    }
    __syncthreads();
#pragma unroll 2
    for (int k = 0; k < 64; k++) {
      float4 av = *(const float4*)&As[k][b0];
      float4 wv = *(const float4*)&Ws[k][j4];
      float aa[4] = {av.x, av.y, av.z, av.w};
      float ww[4] = {wv.x, wv.y, wv.z, wv.w};
#pragma unroll
      for (int ii = 0; ii < 4; ii++)
#pragma unroll
        for (int jj = 0; jj < 4; jj++) acc[ii][jj] += aa[ii] * ww[jj];
    }
  }
#pragma unroll
  for (int ii = 0; ii < 4; ii++)
#pragma unroll
    for (int jj = 0; jj < 4; jj++)
      atomicAdd(&C[(size_t)(b0 + ii) * kO + j0 + j4 + jj], acc[ii][jj]);
}

}  // namespace

extern "C" void kernel_launch(void* const* d_in, const int* in_sizes, int n_in,
                              void* d_out, int out_size, void* d_ws, size_t ws_size,
                              hipStream_t stream) {
  const float* x            = (const float*)d_in[0];
  const float* h_prev       = (const float*)d_in[1];
  const float* c_prev       = (const float*)d_in[2];
  const float* bank         = (const float*)d_in[3];
  const float* read_w_prev  = (const float*)d_in[4];
  const float* write_w_prev = (const float*)d_in[5];
  const float* W_ih         = (const float*)d_in[6];
  const float* W_hh         = (const float*)d_in[7];
  const float* b_ih         = (const float*)d_in[8];
  const float* b_hh         = (const float*)d_in[9];
  const float* read_W       = (const float*)d_in[10];
  const float* read_b       = (const float*)d_in[11];
  const float* write_W      = (const float*)d_in[12];
  const float* write_b      = (const float*)d_in[13];
  const float* out_W        = (const float*)d_in[14];
  const float* out_b        = (const float*)d_in[15];
  float* out = (float*)d_out;

  float* ws    = (float*)d_ws;
  float* gates = ws;                         // 64*2048
  float* praw  = gates + kB * kGates;        // 64*1600
  float* cat   = praw + kB * kPRow;          // 64*896
  float* kwb   = cat + kB * kCatW;           // 3*64*128
  float* krb   = kwb + 3 * kB * kM;
  float* evb   = krb + 3 * kB * kM;
  float* avb   = evb + 3 * kB * kM;
  float* scal  = avb + 3 * kB * kM;          // 6*64*8
  float* sdot  = scal + 6 * kB * 8;          // 64*8
  float* wpack = sdot + kB * 8;              // kWN*8
  float* mA    = wpack + (size_t)kWN * 8;    // kWN*12
  float* mB    = mA + (size_t)kWN * 12;      // kWN*12

  gates_gemm<<<129, 256, 0, stream>>>(x, W_ih, h_prev, W_hh, gates, out_b, out, cat);
  proj_gemm<<<200, 256, 0, stream>>>(gates, b_ih, b_hh, c_prev, write_W, read_W, praw, cat);
  split_params<<<64, 128, 0, stream>>>(praw, write_b, read_b, kwb, krb, evb, avb, scal, sdot);

  passA_k<<<dim3(16, kB), 256, 0, stream>>>(bank, kwb, krb, evb, avb, mA);
  a12_k<<<64, 1024, 0, stream>>>(mA, scal, sdot, read_w_prev, write_w_prev, wpack);
  passB_k<<<dim3(16, kB), 256, 0, stream>>>(bank, wpack, kwb, krb, evb, avb, cat, mB);
  a34_k<<<64, 1024, 0, stream>>>(mB, scal, sdot, read_w_prev, write_w_prev, wpack);
  passC_k<<<dim3(16, kB), 256, 0, stream>>>(bank, wpack, evb, avb, cat);
  out_gemm<<<dim3(kO / 64, kCatW / 128), 256, 0, stream>>>(cat, out_W, out);

  (void)in_sizes; (void)n_in; (void)out_size; (void)ws_size;
}